// Round 1
// baseline (1015.298 us; speedup 1.0000x reference)
//
#include <hip/hip_runtime.h>

// LinkPredictionGNN: 2-layer GCN encode + dot-product decode.
// Strategy: on-device CSR build (by dst) -> atomic-free wave-per-node
// aggregation; fp32 vector GEMM (no fp32 MFMA on CDNA4); 16-lane-per-edge
// decode. All gathers are coalesced full-row loads from LLC-resident tables.

#define IC1 128   // input channels (= hidden channels for conv2 input)
#define OC1 128   // conv1 output channels
#define OC2 64    // conv2 output channels

// Edge-index element: reference says int64, harness doc says int32 possible.
// flag==1 -> int64, flag==0 -> int32 (detected on device).
__device__ __forceinline__ int getIdx(const void* p, long long i, int is64) {
  return is64 ? (int)((const long long*)p)[i] : ((const int*)p)[i];
}

// Classify edge dtype: int32 pairs read as int64 have (second int32)<<32 in the
// high word -> value >= n_nodes almost surely within 4096 samples.
__global__ void k_detect(const void* pei, long long E, int n_nodes, int* flagbuf) {
  __shared__ int bad;
  if (threadIdx.x == 0) bad = 0;
  __syncthreads();
  long long cnt = E < 4096 ? E : 4096;   // <= E int64 slots exist even if data is int32
  const unsigned long long* p64 = (const unsigned long long*)pei;
  for (long long i = threadIdx.x; i < cnt; i += blockDim.x)
    if (p64[i] >= (unsigned long long)n_nodes) bad = 1;   // benign race
  __syncthreads();
  if (threadIdx.x == 0) { flagbuf[0] = bad ? 0 : 1; flagbuf[1] = 0; /* gcur */ }
}

__global__ void k_initdeg(int* deg, int N) {
  int i = blockIdx.x * blockDim.x + threadIdx.x;
  if (i < N) deg[i] = 1;   // self-loop
}

__global__ void k_count(const void* pei, long long E, const int* flagbuf, int* deg) {
  int f = flagbuf[0];
  long long e = (long long)blockIdx.x * blockDim.x + threadIdx.x;
  if (e < E) atomicAdd(&deg[getIdx(pei, E + e, f)], 1);   // dst row = [1][e]
}

// dinv + CSR slot allocation: wave-exclusive-scan of (deg-1), one atomic/wave.
__global__ void k_alloc(const int* deg, float* dinv, int* rowst, int* cursor,
                        int* gcur, int N) {
  int i = blockIdx.x * blockDim.x + threadIdx.x;
  int lane = threadIdx.x & 63;
  int dg = (i < N) ? deg[i] : 1;
  if (i < N) dinv[i] = rsqrtf((float)dg);   // dg >= 1 always (self-loop)
  int cnt = dg - 1;
  int x = cnt;
  #pragma unroll
  for (int off = 1; off < 64; off <<= 1) {
    int y = __shfl_up(x, off);
    if (lane >= off) x += y;
  }
  int base;
  if (lane == 63) base = atomicAdd(gcur, x);   // x@lane63 = wave total
  base = __shfl(base, 63);
  if (i < N) { int st = base + x - cnt; rowst[i] = st; cursor[i] = st; }
}

__global__ void k_fill(const void* pei, long long E, const int* flagbuf,
                       const float* dinv, int* cursor, int* csr_s, float* csr_w) {
  int f = flagbuf[0];
  long long e = (long long)blockIdx.x * blockDim.x + threadIdx.x;
  if (e >= E) return;
  int s = getIdx(pei, e, f);
  int d = getIdx(pei, E + e, f);
  int pos = atomicAdd(&cursor[d], 1);
  csr_s[pos] = s;
  csr_w[pos] = dinv[s] * dinv[d];
}

// t = x @ W   (x: [N,IC1] fp32, W: [IC1,OC] fp32). x tile staged in LDS,
// W read from global (L2-resident, broadcast-coalesced float4).
template<int OC>
__global__ __launch_bounds__(256) void k_gemm(const float* __restrict__ x,
                                              const float* __restrict__ W,
                                              float* __restrict__ t, int N) {
  constexpr int TX = OC / 4;        // threads covering cols (float4 each)
  constexpr int TY = 256 / TX;      // rows per block
  __shared__ float xs[TY][IC1];
  int tx = threadIdx.x % TX, ty = threadIdx.x / TX;
  long long rowBase = (long long)blockIdx.x * TY;
  const float4* xg = (const float4*)(x + rowBase * IC1);
  for (int i = threadIdx.x; i < TY * (IC1 / 4); i += 256) {
    int r = i / (IC1 / 4), c = i % (IC1 / 4);
    if (rowBase + r < N) ((float4*)xs[r])[c] = xg[(long long)r * (IC1 / 4) + c];
  }
  __syncthreads();
  const float4* W4 = (const float4*)W;   // [IC1][TX] float4 view
  float4 acc = {0.f, 0.f, 0.f, 0.f};
  #pragma unroll 4
  for (int k = 0; k < IC1; k += 4) {
    float4 xk = *(const float4*)&xs[ty][k];
    float4 w;
    w = W4[(k + 0) * TX + tx];
    acc.x += xk.x * w.x; acc.y += xk.x * w.y; acc.z += xk.x * w.z; acc.w += xk.x * w.w;
    w = W4[(k + 1) * TX + tx];
    acc.x += xk.y * w.x; acc.y += xk.y * w.y; acc.z += xk.y * w.z; acc.w += xk.y * w.w;
    w = W4[(k + 2) * TX + tx];
    acc.x += xk.z * w.x; acc.y += xk.z * w.y; acc.z += xk.z * w.z; acc.w += xk.z * w.w;
    w = W4[(k + 3) * TX + tx];
    acc.x += xk.w * w.x; acc.y += xk.w * w.y; acc.z += xk.w * w.z; acc.w += xk.w * w.w;
  }
  long long row = rowBase + ty;
  if (row < N) ((float4*)(t + row * OC))[tx] = acc;
}

// out[v] = sum_{e: dst=v} t[src_e]*w_e + t[v]*dinv[v]^2 + bias  (optional relu)
// One wave per node; 64-edge chunks prefetched per-lane then shfl-broadcast.
template<int CH>
__global__ __launch_bounds__(256) void k_agg(const float* __restrict__ t,
                                             float* __restrict__ out,
                                             const int* __restrict__ deg,
                                             const float* __restrict__ dinv,
                                             const int* __restrict__ rowst,
                                             const int* __restrict__ csr_s,
                                             const float* __restrict__ csr_w,
                                             const float* __restrict__ bias,
                                             int N, int relu) {
  constexpr int VPL = CH / 64;   // floats per lane (2 for 128ch, 1 for 64ch)
  long long wid = ((long long)blockIdx.x * blockDim.x + threadIdx.x) >> 6;
  int lane = threadIdx.x & 63;
  if (wid >= N) return;
  int v = (int)wid;
  float dv = dinv[v];
  float sw = dv * dv;            // self-loop norm
  float acc0 = 0.f, acc1 = 0.f;
  const float* tr = t + (long long)v * CH + lane * VPL;
  if constexpr (VPL == 2) { float2 rv = *(const float2*)tr; acc0 = rv.x * sw; acc1 = rv.y * sw; }
  else acc0 = tr[0] * sw;
  int st = rowst[v];
  int cnt = deg[v] - 1;
  for (int base = 0; base < cnt; base += 64) {
    int m = min(64, cnt - base);
    int s = 0; float w = 0.f;
    if (lane < m) { s = csr_s[st + base + lane]; w = csr_w[st + base + lane]; }
    for (int j = 0; j < m; ++j) {
      int ss = __shfl(s, j);
      float ww = __shfl(w, j);
      const float* r = t + (long long)ss * CH + lane * VPL;
      if constexpr (VPL == 2) { float2 rv = *(const float2*)r; acc0 += rv.x * ww; acc1 += rv.y * ww; }
      else acc0 += r[0] * ww;
    }
  }
  float* orow = out + (long long)v * CH + lane * VPL;
  if constexpr (VPL == 2) {
    float o0 = acc0 + bias[lane * 2], o1 = acc1 + bias[lane * 2 + 1];
    if (relu) { o0 = fmaxf(o0, 0.f); o1 = fmaxf(o1, 0.f); }
    *(float2*)orow = make_float2(o0, o1);
  } else {
    float o0 = acc0 + bias[lane];
    if (relu) o0 = fmaxf(o0, 0.f);
    orow[0] = o0;
  }
}

// pred[e] = dot(z[src_e], z[dst_e]) over 64 ch. 16 lanes per edge, float4/lane.
__global__ __launch_bounds__(256) void k_decode(const float* __restrict__ z,
                                                const void* pei, const void* nei,
                                                float* __restrict__ out,
                                                long long E, const int* flagbuf) {
  int f = flagbuf[0];
  long long g = ((long long)blockIdx.x * blockDim.x + threadIdx.x) >> 4;
  int wi = threadIdx.x & 15;
  if (g >= 2 * E) return;
  const void* ei = (g < E) ? pei : nei;
  long long e = (g < E) ? g : g - E;
  int s = getIdx(ei, e, f);
  int d = getIdx(ei, E + e, f);
  float4 a = *(const float4*)(z + (long long)s * OC2 + wi * 4);
  float4 b = *(const float4*)(z + (long long)d * OC2 + wi * 4);
  float p = a.x * b.x + a.y * b.y + a.z * b.z + a.w * b.w;
  p += __shfl_xor(p, 8);
  p += __shfl_xor(p, 4);
  p += __shfl_xor(p, 2);
  p += __shfl_xor(p, 1);
  if (wi == 0) out[g] = p;   // [0,E): pos, [E,2E): neg
}

extern "C" void kernel_launch(void* const* d_in, const int* in_sizes, int n_in,
                              void* d_out, int out_size, void* d_ws, size_t ws_size,
                              hipStream_t stream) {
  const float* x  = (const float*)d_in[0];
  const void*  pei = d_in[1];
  const void*  nei = d_in[2];
  const float* W1 = (const float*)d_in[3];
  const float* b1 = (const float*)d_in[4];
  const float* W2 = (const float*)d_in[5];
  const float* b2 = (const float*)d_in[6];
  float* out = (float*)d_out;

  const int       N = in_sizes[0] / IC1;     // 100000
  const long long E = in_sizes[1] / 2;       // 1600000

  // ---- workspace carve (256B-aligned) ----
  char* p = (char*)d_ws;
  auto carve = [&](size_t bytes) { char* r = p; p += ((bytes + 255) & ~(size_t)255); return r; };
  int*   flagbuf = (int*)  carve(8);                    // [0]=is64, [1]=gcur
  int*   deg     = (int*)  carve((size_t)N * 4);
  float* dinv    = (float*)carve((size_t)N * 4);
  int*   rowst   = (int*)  carve((size_t)N * 4);
  int*   cursor  = (int*)  carve((size_t)N * 4);
  int*   csr_s   = (int*)  carve((size_t)E * 4);
  float* csr_w   = (float*)carve((size_t)E * 4);
  float* bufA    = (float*)carve((size_t)N * IC1 * 4);  // t1 / t2
  float* bufB    = (float*)carve((size_t)N * IC1 * 4);  // h1 / z

  const int B = 256;
  dim3 gN((N + B - 1) / B), gE((unsigned)((E + B - 1) / B));

  // ---- graph structure (shared by both convs) ----
  k_detect<<<1, B, 0, stream>>>(pei, E, N, flagbuf);
  k_initdeg<<<gN, B, 0, stream>>>(deg, N);
  k_count<<<gE, B, 0, stream>>>(pei, E, flagbuf, deg);
  k_alloc<<<gN, B, 0, stream>>>(deg, dinv, rowst, cursor, flagbuf + 1, N);
  k_fill<<<gE, B, 0, stream>>>(pei, E, flagbuf, dinv, cursor, csr_s, csr_w);

  // ---- conv1: t1 = x@W1 -> aggregate -> +b1, relu -> h1 ----
  k_gemm<OC1><<<dim3((N + (256/(OC1/4)) - 1) / (256/(OC1/4))), B, 0, stream>>>(x, W1, bufA, N);
  k_agg<OC1><<<dim3((N + 3) / 4), B, 0, stream>>>(bufA, bufB, deg, dinv, rowst,
                                                  csr_s, csr_w, b1, N, 1);

  // ---- conv2: t2 = h1@W2 -> aggregate -> +b2 -> z ----
  k_gemm<OC2><<<dim3((N + (256/(OC2/4)) - 1) / (256/(OC2/4))), B, 0, stream>>>(bufB, W2, bufA, N);
  k_agg<OC2><<<dim3((N + 3) / 4), B, 0, stream>>>(bufA, bufB, deg, dinv, rowst,
                                                  csr_s, csr_w, b2, N, 0);

  // ---- decode: pos & neg dot products ----
  long long groups = 2 * E;
  dim3 gD((unsigned)((groups * 16 + B - 1) / B));
  k_decode<<<gD, B, 0, stream>>>(bufB, pei, nei, out, E, flagbuf);
}

// Round 2
// 761.391 us; speedup vs baseline: 1.3335x; 1.3335x over previous
//
#include <hip/hip_runtime.h>

// LinkPredictionGNN: 2-layer GCN encode + dot-product decode.
// R1: GEMM rebuilt as LDS-panel GEMM (W k-panels + x tile in LDS, 4x register
// row-blocking) -- was L2-latency-bound at VALUBusy=14%. Aggregation rebuilt
// with float4 gathers, 2-4 edges per load instruction, zero-padded unrolled
// inner loop. CSR build + decode unchanged.

#define IC1 128   // input channels (= hidden channels for conv2 input)
#define OC1 128   // conv1 output channels
#define OC2 64    // conv2 output channels

// Edge-index element: reference says int64, harness doc says int32 possible.
// flag==1 -> int64, flag==0 -> int32 (detected on device).
__device__ __forceinline__ int getIdx(const void* p, long long i, int is64) {
  return is64 ? (int)((const long long*)p)[i] : ((const int*)p)[i];
}

__global__ void k_detect(const void* pei, long long E, int n_nodes, int* flagbuf) {
  __shared__ int bad;
  if (threadIdx.x == 0) bad = 0;
  __syncthreads();
  long long cnt = E < 4096 ? E : 4096;
  const unsigned long long* p64 = (const unsigned long long*)pei;
  for (long long i = threadIdx.x; i < cnt; i += blockDim.x)
    if (p64[i] >= (unsigned long long)n_nodes) bad = 1;   // benign race
  __syncthreads();
  if (threadIdx.x == 0) { flagbuf[0] = bad ? 0 : 1; flagbuf[1] = 0; /* gcur */ }
}

__global__ void k_initdeg(int* deg, int N) {
  int i = blockIdx.x * blockDim.x + threadIdx.x;
  if (i < N) deg[i] = 1;   // self-loop
}

__global__ void k_count(const void* pei, long long E, const int* flagbuf, int* deg) {
  int f = flagbuf[0];
  long long e = (long long)blockIdx.x * blockDim.x + threadIdx.x;
  if (e < E) atomicAdd(&deg[getIdx(pei, E + e, f)], 1);   // dst row = [1][e]
}

// dinv + CSR slot allocation: wave-exclusive-scan of (deg-1), one atomic/wave.
__global__ void k_alloc(const int* deg, float* dinv, int* rowst, int* cursor,
                        int* gcur, int N) {
  int i = blockIdx.x * blockDim.x + threadIdx.x;
  int lane = threadIdx.x & 63;
  int dg = (i < N) ? deg[i] : 1;
  if (i < N) dinv[i] = rsqrtf((float)dg);   // dg >= 1 always (self-loop)
  int cnt = dg - 1;
  int x = cnt;
  #pragma unroll
  for (int off = 1; off < 64; off <<= 1) {
    int y = __shfl_up(x, off);
    if (lane >= off) x += y;
  }
  int base;
  if (lane == 63) base = atomicAdd(gcur, x);   // x@lane63 = wave total
  base = __shfl(base, 63);
  if (i < N) { int st = base + x - cnt; rowst[i] = st; cursor[i] = st; }
}

__global__ void k_fill(const void* pei, long long E, const int* flagbuf,
                       const float* dinv, int* cursor, int* csr_s, float* csr_w) {
  int f = flagbuf[0];
  long long e = (long long)blockIdx.x * blockDim.x + threadIdx.x;
  if (e >= E) return;
  int s = getIdx(pei, e, f);
  int d = getIdx(pei, E + e, f);
  int pos = atomicAdd(&cursor[d], 1);
  csr_s[pos] = s;
  csr_w[pos] = dinv[s] * dinv[d];
}

// t = x @ W. W staged in 32-row k-panels in LDS; x tile in LDS; each thread
// computes RPT=4 rows x 1 float4 col. Inner loop is pure LDS -> VALU.
template<int OC>
__global__ __launch_bounds__(256) void k_gemm(const float* __restrict__ x,
                                              const float* __restrict__ W,
                                              float* __restrict__ t, int N) {
  constexpr int COLV = OC / 4;          // float4 cols per row (32 or 16)
  constexpr int ROWG = 256 / COLV;      // thread row-groups (8 or 16)
  constexpr int RPT  = 4;               // rows per thread
  constexpr int RB   = ROWG * RPT;      // rows per block (32 or 64)
  constexpr int KP   = 32;              // k-panel height
  constexpr int NP   = IC1 / KP;        // panels
  constexpr int XPAD = 4;               // break 2048B row-stride bank aliasing
  __shared__ float Wp[KP * OC];         // 16 KB / 8 KB
  __shared__ float xs[RB][IC1 + XPAD];  // ~17 KB / ~34 KB
  const int tid = threadIdx.x;
  const int tx = tid % COLV, tg = tid / COLV;
  const long long rowBase = (long long)blockIdx.x * RB;
  const float4* Wg = (const float4*)W;
  float4* Wp4 = (float4*)Wp;

  // stage x tile (full K) + W panel 0
  {
    const float4* xg = (const float4*)(x + rowBase * IC1);
    #pragma unroll
    for (int i = tid; i < RB * (IC1 / 4); i += 256) {
      int r = i / (IC1 / 4), c = i % (IC1 / 4);
      float4 v = make_float4(0.f, 0.f, 0.f, 0.f);
      if (rowBase + r < N) v = xg[(long long)r * (IC1 / 4) + c];
      *(float4*)&xs[r][c * 4] = v;
    }
    #pragma unroll
    for (int i = tid; i < KP * COLV; i += 256) Wp4[i] = Wg[i];
  }
  __syncthreads();

  float4 acc[RPT];
  #pragma unroll
  for (int r = 0; r < RPT; ++r) acc[r] = make_float4(0.f, 0.f, 0.f, 0.f);
  const int row0 = tg * RPT;

  for (int p = 0;; ++p) {
    const int kbase = p * KP;
    #pragma unroll 4
    for (int k = 0; k < KP; k += 4) {
      float4 xk[RPT];
      #pragma unroll
      for (int r = 0; r < RPT; ++r) xk[r] = *(const float4*)&xs[row0 + r][kbase + k];
      #pragma unroll
      for (int kk = 0; kk < 4; ++kk) {
        float4 w = Wp4[(k + kk) * COLV + tx];
        #pragma unroll
        for (int r = 0; r < RPT; ++r) {
          float xv = (kk == 0) ? xk[r].x : (kk == 1) ? xk[r].y : (kk == 2) ? xk[r].z : xk[r].w;
          acc[r].x += xv * w.x; acc[r].y += xv * w.y;
          acc[r].z += xv * w.z; acc[r].w += xv * w.w;
        }
      }
    }
    if (p == NP - 1) break;
    __syncthreads();
    #pragma unroll
    for (int i = tid; i < KP * COLV; i += 256) Wp4[i] = Wg[(p + 1) * KP * COLV + i];
    __syncthreads();
  }

  #pragma unroll
  for (int r = 0; r < RPT; ++r) {
    long long row = rowBase + row0 + r;
    if (row < N) ((float4*)(t + row * OC))[tx] = acc[r];
  }
}

// out[v] = sum_{e: dst=v} t[src_e]*w_e + t[v]*dinv[v]^2 + bias (optional relu)
// One wave per node. Wave splits into EPI edge-slots of G lanes; each slot
// gathers a full row as float4/lane -> 2-4 edges per load instruction.
// Padded (s=0,w=0) edges make the inner loop shape unroll-friendly.
template<int CH>
__global__ __launch_bounds__(256) void k_agg(const float* __restrict__ t,
                                             float* __restrict__ out,
                                             const int* __restrict__ deg,
                                             const float* __restrict__ dinv,
                                             const int* __restrict__ rowst,
                                             const int* __restrict__ csr_s,
                                             const float* __restrict__ csr_w,
                                             const float* __restrict__ bias,
                                             int N, int relu) {
  constexpr int G   = CH / 4;   // lanes per edge row (32 or 16)
  constexpr int EPI = 64 / G;   // edges per iteration (2 or 4)
  long long wid = ((long long)blockIdx.x * blockDim.x + threadIdx.x) >> 6;
  int lane = threadIdx.x & 63;
  if (wid >= N) return;
  int v = (int)wid;
  int sub = lane / G;           // edge slot
  int cl  = lane % G;           // float4 col within row
  float dv = dinv[v];
  float selfw = (sub == 0) ? dv * dv : 0.f;
  float4 acc;
  {
    float4 rv = ((const float4*)(t + (long long)v * CH))[cl];
    acc.x = rv.x * selfw; acc.y = rv.y * selfw;
    acc.z = rv.z * selfw; acc.w = rv.w * selfw;
  }
  int st = rowst[v];
  int cnt = deg[v] - 1;
  for (int base = 0; base < cnt; base += 64) {
    int m = min(64, cnt - base);
    int s = 0; float w = 0.f;
    if (lane < m) { s = csr_s[st + base + lane]; w = csr_w[st + base + lane]; }
    int iters = (m + EPI - 1) / EPI;
    #pragma unroll 4
    for (int j = 0; j < iters; ++j) {
      int src  = __shfl(s, j * EPI + sub);   // padded lanes give s=0,w=0
      float ww = __shfl(w, j * EPI + sub);
      float4 rv = ((const float4*)(t + (long long)src * CH))[cl];
      acc.x += rv.x * ww; acc.y += rv.y * ww;
      acc.z += rv.z * ww; acc.w += rv.w * ww;
    }
  }
  #pragma unroll
  for (int off = G; off < 64; off <<= 1) {
    acc.x += __shfl_xor(acc.x, off);
    acc.y += __shfl_xor(acc.y, off);
    acc.z += __shfl_xor(acc.z, off);
    acc.w += __shfl_xor(acc.w, off);
  }
  if (sub == 0) {
    float4 bb = ((const float4*)bias)[cl];
    float4 o = make_float4(acc.x + bb.x, acc.y + bb.y, acc.z + bb.z, acc.w + bb.w);
    if (relu) {
      o.x = fmaxf(o.x, 0.f); o.y = fmaxf(o.y, 0.f);
      o.z = fmaxf(o.z, 0.f); o.w = fmaxf(o.w, 0.f);
    }
    ((float4*)(out + (long long)v * CH))[cl] = o;
  }
}

// pred[e] = dot(z[src_e], z[dst_e]) over 64 ch. 16 lanes per edge, float4/lane.
__global__ __launch_bounds__(256) void k_decode(const float* __restrict__ z,
                                                const void* pei, const void* nei,
                                                float* __restrict__ out,
                                                long long E, const int* flagbuf) {
  int f = flagbuf[0];
  long long g = ((long long)blockIdx.x * blockDim.x + threadIdx.x) >> 4;
  int wi = threadIdx.x & 15;
  if (g >= 2 * E) return;
  const void* ei = (g < E) ? pei : nei;
  long long e = (g < E) ? g : g - E;
  int s = getIdx(ei, e, f);
  int d = getIdx(ei, E + e, f);
  float4 a = *(const float4*)(z + (long long)s * OC2 + wi * 4);
  float4 b = *(const float4*)(z + (long long)d * OC2 + wi * 4);
  float p = a.x * b.x + a.y * b.y + a.z * b.z + a.w * b.w;
  p += __shfl_xor(p, 8);
  p += __shfl_xor(p, 4);
  p += __shfl_xor(p, 2);
  p += __shfl_xor(p, 1);
  if (wi == 0) out[g] = p;   // [0,E): pos, [E,2E): neg
}

extern "C" void kernel_launch(void* const* d_in, const int* in_sizes, int n_in,
                              void* d_out, int out_size, void* d_ws, size_t ws_size,
                              hipStream_t stream) {
  const float* x  = (const float*)d_in[0];
  const void*  pei = d_in[1];
  const void*  nei = d_in[2];
  const float* W1 = (const float*)d_in[3];
  const float* b1 = (const float*)d_in[4];
  const float* W2 = (const float*)d_in[5];
  const float* b2 = (const float*)d_in[6];
  float* out = (float*)d_out;

  const int       N = in_sizes[0] / IC1;     // 100000
  const long long E = in_sizes[1] / 2;       // 1600000

  // ---- workspace carve (256B-aligned) ----
  char* p = (char*)d_ws;
  auto carve = [&](size_t bytes) { char* r = p; p += ((bytes + 255) & ~(size_t)255); return r; };
  int*   flagbuf = (int*)  carve(8);                    // [0]=is64, [1]=gcur
  int*   deg     = (int*)  carve((size_t)N * 4);
  float* dinv    = (float*)carve((size_t)N * 4);
  int*   rowst   = (int*)  carve((size_t)N * 4);
  int*   cursor  = (int*)  carve((size_t)N * 4);
  int*   csr_s   = (int*)  carve((size_t)E * 4);
  float* csr_w   = (float*)carve((size_t)E * 4);
  float* bufA    = (float*)carve((size_t)N * IC1 * 4);  // t1 / t2
  float* bufB    = (float*)carve((size_t)N * IC1 * 4);  // h1 / z

  const int B = 256;
  dim3 gN((N + B - 1) / B), gE((unsigned)((E + B - 1) / B));

  // ---- graph structure (shared by both convs) ----
  k_detect<<<1, B, 0, stream>>>(pei, E, N, flagbuf);
  k_initdeg<<<gN, B, 0, stream>>>(deg, N);
  k_count<<<gE, B, 0, stream>>>(pei, E, flagbuf, deg);
  k_alloc<<<gN, B, 0, stream>>>(deg, dinv, rowst, cursor, flagbuf + 1, N);
  k_fill<<<gE, B, 0, stream>>>(pei, E, flagbuf, dinv, cursor, csr_s, csr_w);

  // ---- conv1: t1 = x@W1 -> aggregate -> +b1, relu -> h1 ----
  {
    constexpr int RB1 = (256 / (OC1 / 4)) * 4;   // 32
    k_gemm<OC1><<<dim3((N + RB1 - 1) / RB1), B, 0, stream>>>(x, W1, bufA, N);
  }
  k_agg<OC1><<<dim3((N + 3) / 4), B, 0, stream>>>(bufA, bufB, deg, dinv, rowst,
                                                  csr_s, csr_w, b1, N, 1);

  // ---- conv2: t2 = h1@W2 -> aggregate -> +b2 -> z ----
  {
    constexpr int RB2 = (256 / (OC2 / 4)) * 4;   // 64
    k_gemm<OC2><<<dim3((N + RB2 - 1) / RB2), B, 0, stream>>>(bufB, W2, bufA, N);
  }
  k_agg<OC2><<<dim3((N + 3) / 4), B, 0, stream>>>(bufA, bufB, deg, dinv, rowst,
                                                  csr_s, csr_w, b2, N, 0);

  // ---- decode: pos & neg dot products ----
  long long groups = 2 * E;
  dim3 gD((unsigned)((groups * 16 + B - 1) / B));
  k_decode<<<gD, B, 0, stream>>>(bufB, pei, nei, out, E, flagbuf);
}

// Round 3
// 574.079 us; speedup vs baseline: 1.7686x; 1.3263x over previous
//
#include <hip/hip_runtime.h>

// LinkPredictionGNN: 2-layer GCN encode + dot-product decode.
// R2: all intermediate feature tables (t1, h1, t2, z) stored as bf16 with
// fp32 accumulation -- halves bytes of every gather-bound kernel (agg, decode,
// gemm2 staging). CSR entries packed as int2 {src, weight-bits}. The gather
// kernels are traffic-bound at the random-gather ceiling (~3.5 TB/s HBM-side,
// R1 profile), so bytes are the only lever left.

#define IC1 128   // input channels (= hidden channels for conv2 input)
#define OC1 128   // conv1 output channels
#define OC2 64    // conv2 output channels

typedef unsigned int u32;
typedef unsigned short u16;

// ---- bf16 helpers (RNE pack, bit-shift unpack) ----
__device__ __forceinline__ u16 f2bf(float f) {
  u32 u = __float_as_uint(f);
  u32 r = (u + 0x7fffu + ((u >> 16) & 1u)) >> 16;
  return (u16)r;
}
__device__ __forceinline__ u32 pack2bf(float lo, float hi) {
  return (u32)f2bf(lo) | ((u32)f2bf(hi) << 16);
}
__device__ __forceinline__ float bflo(u32 w) { return __uint_as_float(w << 16); }
__device__ __forceinline__ float bfhi(u32 w) { return __uint_as_float(w & 0xffff0000u); }

// Edge-index element: reference says int64, harness doc says int32 possible.
// flag==1 -> int64, flag==0 -> int32 (detected on device).
__device__ __forceinline__ int getIdx(const void* p, long long i, int is64) {
  return is64 ? (int)((const long long*)p)[i] : ((const int*)p)[i];
}

__global__ void k_detect(const void* pei, long long E, int n_nodes, int* flagbuf) {
  __shared__ int bad;
  if (threadIdx.x == 0) bad = 0;
  __syncthreads();
  long long cnt = E < 4096 ? E : 4096;
  const unsigned long long* p64 = (const unsigned long long*)pei;
  for (long long i = threadIdx.x; i < cnt; i += blockDim.x)
    if (p64[i] >= (unsigned long long)n_nodes) bad = 1;   // benign race
  __syncthreads();
  if (threadIdx.x == 0) { flagbuf[0] = bad ? 0 : 1; flagbuf[1] = 0; /* gcur */ }
}

__global__ void k_initdeg(int* deg, int N) {
  int i = blockIdx.x * blockDim.x + threadIdx.x;
  if (i < N) deg[i] = 1;   // self-loop
}

__global__ void k_count(const void* pei, long long E, const int* flagbuf, int* deg) {
  int f = flagbuf[0];
  long long e = (long long)blockIdx.x * blockDim.x + threadIdx.x;
  if (e < E) atomicAdd(&deg[getIdx(pei, E + e, f)], 1);   // dst row = [1][e]
}

// dinv + CSR slot allocation: wave-exclusive-scan of (deg-1), one atomic/wave.
__global__ void k_alloc(const int* deg, float* dinv, int* rowst, int* cursor,
                        int* gcur, int N) {
  int i = blockIdx.x * blockDim.x + threadIdx.x;
  int lane = threadIdx.x & 63;
  int dg = (i < N) ? deg[i] : 1;
  if (i < N) dinv[i] = rsqrtf((float)dg);   // dg >= 1 always (self-loop)
  int cnt = dg - 1;
  int x = cnt;
  #pragma unroll
  for (int off = 1; off < 64; off <<= 1) {
    int y = __shfl_up(x, off);
    if (lane >= off) x += y;
  }
  int base;
  if (lane == 63) base = atomicAdd(gcur, x);   // x@lane63 = wave total
  base = __shfl(base, 63);
  if (i < N) { int st = base + x - cnt; rowst[i] = st; cursor[i] = st; }
}

__global__ void k_fill(const void* pei, long long E, const int* flagbuf,
                       const float* dinv, int* cursor, int2* csr) {
  int f = flagbuf[0];
  long long e = (long long)blockIdx.x * blockDim.x + threadIdx.x;
  if (e >= E) return;
  int s = getIdx(pei, e, f);
  int d = getIdx(pei, E + e, f);
  int pos = atomicAdd(&cursor[d], 1);
  csr[pos] = make_int2(s, __float_as_int(dinv[s] * dinv[d]));
}

// t = x @ W (bf16 out). W staged in 32-row k-panels in LDS; x tile in LDS
// (fp32, converted at stage time if input is bf16); RPT=4 rows x float4 col.
template<int OC, bool BF16IN>
__global__ __launch_bounds__(256) void k_gemm(const void* __restrict__ xin,
                                              const float* __restrict__ W,
                                              u16* __restrict__ t, int N) {
  constexpr int COLV = OC / 4;          // float4 cols per row (32 or 16)
  constexpr int ROWG = 256 / COLV;      // thread row-groups (8 or 16)
  constexpr int RPT  = 4;               // rows per thread
  constexpr int RB   = ROWG * RPT;      // rows per block (32 or 64)
  constexpr int KP   = 32;              // k-panel height
  constexpr int NP   = IC1 / KP;        // panels
  constexpr int XPAD = 4;               // break 2048B row-stride bank aliasing
  __shared__ float Wp[KP * OC];
  __shared__ float xs[RB][IC1 + XPAD];
  const int tid = threadIdx.x;
  const int tx = tid % COLV, tg = tid / COLV;
  const long long rowBase = (long long)blockIdx.x * RB;
  const float4* Wg = (const float4*)W;
  float4* Wp4 = (float4*)Wp;

  // stage x tile (full K) + W panel 0
  if constexpr (BF16IN) {
    const u16* xg = (const u16*)xin + rowBase * IC1;
    #pragma unroll
    for (int i = tid; i < RB * (IC1 / 8); i += 256) {
      int r = i / (IC1 / 8), c = i % (IC1 / 8);
      uint4 v = make_uint4(0u, 0u, 0u, 0u);
      if (rowBase + r < N) v = ((const uint4*)(xg + (long long)r * IC1))[c];
      float* dst = &xs[r][c * 8];
      dst[0] = bflo(v.x); dst[1] = bfhi(v.x);
      dst[2] = bflo(v.y); dst[3] = bfhi(v.y);
      dst[4] = bflo(v.z); dst[5] = bfhi(v.z);
      dst[6] = bflo(v.w); dst[7] = bfhi(v.w);
    }
  } else {
    const float4* xg = (const float4*)((const float*)xin + rowBase * IC1);
    #pragma unroll
    for (int i = tid; i < RB * (IC1 / 4); i += 256) {
      int r = i / (IC1 / 4), c = i % (IC1 / 4);
      float4 v = make_float4(0.f, 0.f, 0.f, 0.f);
      if (rowBase + r < N) v = xg[(long long)r * (IC1 / 4) + c];
      *(float4*)&xs[r][c * 4] = v;
    }
  }
  #pragma unroll
  for (int i = tid; i < KP * COLV; i += 256) Wp4[i] = Wg[i];
  __syncthreads();

  float4 acc[RPT];
  #pragma unroll
  for (int r = 0; r < RPT; ++r) acc[r] = make_float4(0.f, 0.f, 0.f, 0.f);
  const int row0 = tg * RPT;

  for (int p = 0;; ++p) {
    const int kbase = p * KP;
    #pragma unroll 4
    for (int k = 0; k < KP; k += 4) {
      float4 xk[RPT];
      #pragma unroll
      for (int r = 0; r < RPT; ++r) xk[r] = *(const float4*)&xs[row0 + r][kbase + k];
      #pragma unroll
      for (int kk = 0; kk < 4; ++kk) {
        float4 w = Wp4[(k + kk) * COLV + tx];
        #pragma unroll
        for (int r = 0; r < RPT; ++r) {
          float xv = (kk == 0) ? xk[r].x : (kk == 1) ? xk[r].y : (kk == 2) ? xk[r].z : xk[r].w;
          acc[r].x += xv * w.x; acc[r].y += xv * w.y;
          acc[r].z += xv * w.z; acc[r].w += xv * w.w;
        }
      }
    }
    if (p == NP - 1) break;
    __syncthreads();
    #pragma unroll
    for (int i = tid; i < KP * COLV; i += 256) Wp4[i] = Wg[(p + 1) * KP * COLV + i];
    __syncthreads();
  }

  #pragma unroll
  for (int r = 0; r < RPT; ++r) {
    long long row = rowBase + row0 + r;
    if (row < N)
      ((uint2*)((u16*)t + row * OC))[tx] =
          make_uint2(pack2bf(acc[r].x, acc[r].y), pack2bf(acc[r].z, acc[r].w));
  }
}

// out[v] = sum_{e: dst=v} t[src_e]*w_e + t[v]*dinv[v]^2 + bias (optional relu)
// One wave per node; G=CH/8 lanes per row (16B bf16x8 per lane), EPI=64/G
// edges gathered per iteration. fp32 accumulate, bf16 out.
template<int CH>
__global__ __launch_bounds__(256) void k_agg(const u16* __restrict__ t,
                                             u16* __restrict__ out,
                                             const int* __restrict__ deg,
                                             const float* __restrict__ dinv,
                                             const int* __restrict__ rowst,
                                             const int2* __restrict__ csr,
                                             const float* __restrict__ bias,
                                             int N, int relu) {
  constexpr int G   = CH / 8;   // lanes per edge row (16 or 8)
  constexpr int EPI = 64 / G;   // edges per iteration (4 or 8)
  long long wid = ((long long)blockIdx.x * blockDim.x + threadIdx.x) >> 6;
  int lane = threadIdx.x & 63;
  if (wid >= N) return;
  int v = (int)wid;
  int sub = lane / G;           // edge slot
  int cl  = lane % G;           // 16B chunk within row
  float dv = dinv[v];
  float selfw = (sub == 0) ? dv * dv : 0.f;
  float acc[8];
  {
    uint4 u = ((const uint4*)(t + (long long)v * CH))[cl];
    acc[0] = bflo(u.x) * selfw; acc[1] = bfhi(u.x) * selfw;
    acc[2] = bflo(u.y) * selfw; acc[3] = bfhi(u.y) * selfw;
    acc[4] = bflo(u.z) * selfw; acc[5] = bfhi(u.z) * selfw;
    acc[6] = bflo(u.w) * selfw; acc[7] = bfhi(u.w) * selfw;
  }
  int st = rowst[v];
  int cnt = deg[v] - 1;
  for (int base = 0; base < cnt; base += 64) {
    int m = min(64, cnt - base);
    int s = 0; float w = 0.f;
    if (lane < m) { int2 e = csr[st + base + lane]; s = e.x; w = __int_as_float(e.y); }
    int iters = (m + EPI - 1) / EPI;
    #pragma unroll 2
    for (int j = 0; j < iters; ++j) {
      int src  = __shfl(s, j * EPI + sub);   // padded lanes give s=0,w=0
      float ww = __shfl(w, j * EPI + sub);
      uint4 u = ((const uint4*)(t + (long long)src * CH))[cl];
      acc[0] += bflo(u.x) * ww; acc[1] += bfhi(u.x) * ww;
      acc[2] += bflo(u.y) * ww; acc[3] += bfhi(u.y) * ww;
      acc[4] += bflo(u.z) * ww; acc[5] += bfhi(u.z) * ww;
      acc[6] += bflo(u.w) * ww; acc[7] += bfhi(u.w) * ww;
    }
  }
  #pragma unroll
  for (int off = G; off < 64; off <<= 1) {
    #pragma unroll
    for (int i = 0; i < 8; ++i) acc[i] += __shfl_xor(acc[i], off);
  }
  if (sub == 0) {
    float4 b0 = ((const float4*)bias)[cl * 2];
    float4 b1 = ((const float4*)bias)[cl * 2 + 1];
    float o[8] = {acc[0] + b0.x, acc[1] + b0.y, acc[2] + b0.z, acc[3] + b0.w,
                  acc[4] + b1.x, acc[5] + b1.y, acc[6] + b1.z, acc[7] + b1.w};
    if (relu) {
      #pragma unroll
      for (int i = 0; i < 8; ++i) o[i] = fmaxf(o[i], 0.f);
    }
    uint4 w4;
    w4.x = pack2bf(o[0], o[1]); w4.y = pack2bf(o[2], o[3]);
    w4.z = pack2bf(o[4], o[5]); w4.w = pack2bf(o[6], o[7]);
    ((uint4*)(out + (long long)v * CH))[cl] = w4;
  }
}

// pred[e] = dot(z[src_e], z[dst_e]) over 64 bf16 ch. 8 lanes/edge, 16B/lane.
__global__ __launch_bounds__(256) void k_decode(const u16* __restrict__ z,
                                                const void* pei, const void* nei,
                                                float* __restrict__ out,
                                                long long E, const int* flagbuf) {
  int f = flagbuf[0];
  long long g = ((long long)blockIdx.x * blockDim.x + threadIdx.x) >> 3;
  int wi = threadIdx.x & 7;
  if (g >= 2 * E) return;
  const void* ei = (g < E) ? pei : nei;
  long long e = (g < E) ? g : g - E;
  int s = getIdx(ei, e, f);
  int d = getIdx(ei, E + e, f);
  uint4 a = ((const uint4*)(z + (long long)s * OC2))[wi];
  uint4 b = ((const uint4*)(z + (long long)d * OC2))[wi];
  float p = bflo(a.x) * bflo(b.x) + bfhi(a.x) * bfhi(b.x)
          + bflo(a.y) * bflo(b.y) + bfhi(a.y) * bfhi(b.y)
          + bflo(a.z) * bflo(b.z) + bfhi(a.z) * bfhi(b.z)
          + bflo(a.w) * bflo(b.w) + bfhi(a.w) * bfhi(b.w);
  p += __shfl_xor(p, 4);
  p += __shfl_xor(p, 2);
  p += __shfl_xor(p, 1);
  if (wi == 0) out[g] = p;   // [0,E): pos, [E,2E): neg
}

extern "C" void kernel_launch(void* const* d_in, const int* in_sizes, int n_in,
                              void* d_out, int out_size, void* d_ws, size_t ws_size,
                              hipStream_t stream) {
  const float* x  = (const float*)d_in[0];
  const void*  pei = d_in[1];
  const void*  nei = d_in[2];
  const float* W1 = (const float*)d_in[3];
  const float* b1 = (const float*)d_in[4];
  const float* W2 = (const float*)d_in[5];
  const float* b2 = (const float*)d_in[6];
  float* out = (float*)d_out;

  const int       N = in_sizes[0] / IC1;     // 100000
  const long long E = in_sizes[1] / 2;       // 1600000

  // ---- workspace carve (256B-aligned) ----
  char* p = (char*)d_ws;
  auto carve = [&](size_t bytes) { char* r = p; p += ((bytes + 255) & ~(size_t)255); return r; };
  int*   flagbuf = (int*)  carve(8);                    // [0]=is64, [1]=gcur
  int*   deg     = (int*)  carve((size_t)N * 4);
  float* dinv    = (float*)carve((size_t)N * 4);
  int*   rowst   = (int*)  carve((size_t)N * 4);
  int*   cursor  = (int*)  carve((size_t)N * 4);
  int2*  csr     = (int2*) carve((size_t)E * 8);
  u16*   bufA    = (u16*)  carve((size_t)N * IC1 * 2);  // t1 / t2 (bf16)
  u16*   bufB    = (u16*)  carve((size_t)N * IC1 * 2);  // h1 / z  (bf16)

  const int B = 256;
  dim3 gN((N + B - 1) / B), gE((unsigned)((E + B - 1) / B));

  // ---- graph structure (shared by both convs) ----
  k_detect<<<1, B, 0, stream>>>(pei, E, N, flagbuf);
  k_initdeg<<<gN, B, 0, stream>>>(deg, N);
  k_count<<<gE, B, 0, stream>>>(pei, E, flagbuf, deg);
  k_alloc<<<gN, B, 0, stream>>>(deg, dinv, rowst, cursor, flagbuf + 1, N);
  k_fill<<<gE, B, 0, stream>>>(pei, E, flagbuf, dinv, cursor, csr);

  // ---- conv1: t1 = x@W1 -> aggregate -> +b1, relu -> h1 ----
  k_gemm<OC1, false><<<dim3((N + 31) / 32), B, 0, stream>>>(x, W1, bufA, N);
  k_agg<OC1><<<dim3((N + 3) / 4), B, 0, stream>>>(bufA, bufB, deg, dinv, rowst,
                                                  csr, b1, N, 1);

  // ---- conv2: t2 = h1@W2 -> aggregate -> +b2 -> z ----
  k_gemm<OC2, true><<<dim3((N + 63) / 64), B, 0, stream>>>(bufB, W2, bufA, N);
  k_agg<OC2><<<dim3((N + 3) / 4), B, 0, stream>>>(bufA, bufB, deg, dinv, rowst,
                                                  csr, b2, N, 0);

  // ---- decode: pos & neg dot products ----
  long long groups = 2 * E;
  dim3 gD((unsigned)((groups * 8 + B - 1) / B));
  k_decode<<<gD, B, 0, stream>>>(bufB, pei, nei, out, E, flagbuf);
}

// Round 4
// 547.651 us; speedup vs baseline: 1.8539x; 1.0483x over previous
//
#include <hip/hip_runtime.h>

// LinkPredictionGNN: 2-layer GCN encode + dot-product decode.
// R3: CSR build rewritten as bucketed two-phase partition. The old k_fill was
// a random 8B scatter -> 101 MB HBM writes for 12.8 MB payload (full 64B
// write-allocate amplification, cross-XCD partial lines). New pipeline:
// hist (per-bucket LDS histogram + deg atomics) -> scan -> bin (LDS-staged
// partition into bucket-contiguous runs) -> fill2 (per-bucket block, scatter
// confined to a 32KB window on one XCD -> full-line writes). CSR entry is
// 4B (src only); w = dinv[s]*dinv[v] recomputed in agg from L2-hot dinv.

#define IC1 128   // input channels (= hidden channels for conv2 input)
#define OC1 128   // conv1 output channels
#define OC2 64    // conv2 output channels

#define BSH    9            // bucket shift: 512 nodes per bucket
#define BNODES (1 << BSH)
#define NBMAX  512          // supports N <= 262144 (N = 100000 here)
#define CHB    8192         // edges per k_bin block
#define CHH    4096         // edges per k_hist block
// pack: src in bits [0,20), d_local in bits [20,29)  (requires N < 2^20)

typedef unsigned int u32;
typedef unsigned short u16;

// ---- bf16 helpers (RNE pack, bit-shift unpack) ----
__device__ __forceinline__ u16 f2bf(float f) {
  u32 u = __float_as_uint(f);
  u32 r = (u + 0x7fffu + ((u >> 16) & 1u)) >> 16;
  return (u16)r;
}
__device__ __forceinline__ u32 pack2bf(float lo, float hi) {
  return (u32)f2bf(lo) | ((u32)f2bf(hi) << 16);
}
__device__ __forceinline__ float bflo(u32 w) { return __uint_as_float(w << 16); }
__device__ __forceinline__ float bfhi(u32 w) { return __uint_as_float(w & 0xffff0000u); }

// Edge-index element: int64 per reference, int32 possible per harness doc.
__device__ __forceinline__ int getIdx(const void* p, long long i, int is64) {
  return is64 ? (int)((const long long*)p)[i] : ((const int*)p)[i];
}

__global__ void k_detect(const void* pei, long long E, int n_nodes, int* flagbuf) {
  __shared__ int bad;
  if (threadIdx.x == 0) bad = 0;
  __syncthreads();
  long long cnt = E < 4096 ? E : 4096;
  const unsigned long long* p64 = (const unsigned long long*)pei;
  for (long long i = threadIdx.x; i < cnt; i += blockDim.x)
    if (p64[i] >= (unsigned long long)n_nodes) bad = 1;   // benign race
  __syncthreads();
  if (threadIdx.x == 0) flagbuf[0] = bad ? 0 : 1;
}

__global__ void k_init(int* deg, int* bcnt, int N, int NB) {
  int i = blockIdx.x * blockDim.x + threadIdx.x;
  if (i < N) deg[i] = 1;   // self-loop
  if (i < NB) bcnt[i] = 0;
}

// Per-bucket edge histogram (LDS-first) + destination degree atomics.
__global__ __launch_bounds__(256) void k_hist(const void* pei, long long E,
                                              const int* flagbuf, int* deg,
                                              int* bcnt, int NB) {
  __shared__ int h[NBMAX];
  int f = flagbuf[0];
  for (int i = threadIdx.x; i < NB; i += 256) h[i] = 0;
  __syncthreads();
  long long e0 = (long long)blockIdx.x * CHH;
  long long e1 = min(E, e0 + CHH);
  for (long long e = e0 + threadIdx.x; e < e1; e += 256) {
    int d = getIdx(pei, E + e, f);
    atomicAdd(&deg[d], 1);
    atomicAdd(&h[d >> BSH], 1);
  }
  __syncthreads();
  for (int i = threadIdx.x; i < NB; i += 256)
    if (h[i]) atomicAdd(&bcnt[i], h[i]);
}

// Single-block exclusive scan of bucket counts -> boff / gcur; totals.
__global__ __launch_bounds__(256) void k_scan(const int* bcnt, int* boff,
                                              int* gcur, int* rowst, int NB, int N) {
  __shared__ int sa[256];
  __shared__ int carryS;
  if (threadIdx.x == 0) carryS = 0;
  __syncthreads();
  for (int base = 0; base < NB; base += 256) {
    int i = base + threadIdx.x;
    int v = (i < NB) ? bcnt[i] : 0;
    sa[threadIdx.x] = v;
    __syncthreads();
    for (int off = 1; off < 256; off <<= 1) {
      int t = (threadIdx.x >= off) ? sa[threadIdx.x - off] : 0;
      __syncthreads();
      sa[threadIdx.x] += t;
      __syncthreads();
    }
    int exc = sa[threadIdx.x] - v + carryS;
    if (i < NB) { boff[i] = exc; gcur[i] = exc; }
    __syncthreads();
    if (threadIdx.x == 255) carryS += sa[255];
    __syncthreads();
  }
  if (threadIdx.x == 0) { boff[NB] = carryS; rowst[N] = carryS; }
}

// LDS-staged partition: sort a CHB-edge chunk by bucket in LDS, flush each
// bucket's run contiguously to global binned[] (one cursor atomic per bucket).
__global__ __launch_bounds__(256) void k_bin(const void* pei, long long E,
                                             const int* flagbuf, int* gcur,
                                             u32* binned, int NB) {
  __shared__ u32 stage[CHB];
  __shared__ int h[NBMAX], lofs[NBMAX + 1], cur[NBMAX], gofs[NBMAX];
  __shared__ int sa[256];
  __shared__ int carryS;
  int f = flagbuf[0];
  int tid = threadIdx.x;
  for (int i = tid; i < NB; i += 256) h[i] = 0;
  if (tid == 0) carryS = 0;
  __syncthreads();
  long long e0 = (long long)blockIdx.x * CHB;
  long long e1 = min(E, e0 + CHB);
  int cc = (int)(e1 - e0);
  for (long long e = e0 + tid; e < e1; e += 256)
    atomicAdd(&h[getIdx(pei, E + e, f) >> BSH], 1);
  __syncthreads();
  // exclusive scan h -> lofs
  for (int base = 0; base < NB; base += 256) {
    int i = base + tid;
    int v = (i < NB) ? h[i] : 0;
    sa[tid] = v;
    __syncthreads();
    for (int off = 1; off < 256; off <<= 1) {
      int t = (tid >= off) ? sa[tid - off] : 0;
      __syncthreads();
      sa[tid] += t;
      __syncthreads();
    }
    int exc = sa[tid] - v + carryS;
    if (i < NB) { lofs[i] = exc; cur[i] = exc; }
    __syncthreads();
    if (tid == 255) carryS += sa[255];
    __syncthreads();
  }
  if (tid == 0) lofs[NB] = cc;
  __syncthreads();
  // scatter chunk into LDS staging, bucket-grouped
  for (long long e = e0 + tid; e < e1; e += 256) {
    int s = getIdx(pei, e, f);
    int d = getIdx(pei, E + e, f);
    int b = d >> BSH;
    int p = atomicAdd(&cur[b], 1);
    stage[p] = (u32)s | ((u32)(d & (BNODES - 1)) << 20);
  }
  __syncthreads();
  // claim global space per bucket
  for (int b = tid; b < NB; b += 256) {
    int cnt = cur[b] - lofs[b];
    gofs[b] = cnt ? (atomicAdd(&gcur[b], cnt) - lofs[b]) : 0;
  }
  __syncthreads();
  // flush: consecutive LDS slots -> consecutive global slots within each run
  for (int i = tid; i < cc; i += 256) {
    int lo = 0, hi = NB;   // invariant: lofs[lo] <= i < lofs[hi]
    while (hi - lo > 1) {
      int mid = (lo + hi) >> 1;
      if (lofs[mid] <= i) lo = mid; else hi = mid;
    }
    binned[(long long)i + gofs[lo]] = stage[i];
  }
}

// One block per bucket: local deg-scan -> rowst + dinv; scatter bucket edges
// into the bucket's contiguous csr window (single XCD -> full-line writes).
__global__ __launch_bounds__(256) void k_fill2(const u32* __restrict__ binned,
                                               const int* __restrict__ boff,
                                               const int* __restrict__ deg,
                                               float* __restrict__ dinv,
                                               int* __restrict__ rowst,
                                               u32* __restrict__ csr, int N) {
  __shared__ int sa[BNODES], sb[BNODES], cursor[BNODES];
  int b = blockIdx.x;
  int v0 = b << BSH;
  int nv = min(BNODES, N - v0);
  int tid = threadIdx.x;
  for (int i = tid; i < BNODES; i += 256) sa[i] = (i < nv) ? (deg[v0 + i] - 1) : 0;
  __syncthreads();
  int* A = sa; int* B = sb;
  #pragma unroll 1
  for (int off = 1; off < BNODES; off <<= 1) {   // inclusive Hillis-Steele
    for (int i = tid; i < BNODES; i += 256)
      B[i] = A[i] + ((i >= off) ? A[i - off] : 0);
    __syncthreads();
    int* t = A; A = B; B = t;
  }
  int base = boff[b];
  for (int i = tid; i < nv; i += 256) {
    int dg = deg[v0 + i];
    int exc = A[i] - (dg - 1);
    rowst[v0 + i] = base + exc;
    cursor[i] = exc;
    dinv[v0 + i] = rsqrtf((float)dg);
  }
  __syncthreads();
  int j1 = boff[b + 1];
  for (int j = base + tid; j < j1; j += 256) {
    u32 u = binned[j];
    int s = (int)(u & 0xFFFFFu);
    int dl = (int)(u >> 20);
    int p = atomicAdd(&cursor[dl], 1);
    csr[base + p] = (u32)s;
  }
}

// t = x @ W (bf16 out). W staged in 32-row k-panels in LDS; x tile in LDS
// (fp32, converted at stage time if input is bf16); RPT=4 rows x float4 col.
template<int OC, bool BF16IN>
__global__ __launch_bounds__(256) void k_gemm(const void* __restrict__ xin,
                                              const float* __restrict__ W,
                                              u16* __restrict__ t, int N) {
  constexpr int COLV = OC / 4;          // float4 cols per row (32 or 16)
  constexpr int ROWG = 256 / COLV;      // thread row-groups (8 or 16)
  constexpr int RPT  = 4;               // rows per thread
  constexpr int RB   = ROWG * RPT;      // rows per block (32 or 64)
  constexpr int KP   = 32;              // k-panel height
  constexpr int NP   = IC1 / KP;        // panels
  constexpr int XPAD = 4;               // break 2048B row-stride bank aliasing
  __shared__ float Wp[KP * OC];
  __shared__ float xs[RB][IC1 + XPAD];
  const int tid = threadIdx.x;
  const int tx = tid % COLV, tg = tid / COLV;
  const long long rowBase = (long long)blockIdx.x * RB;
  const float4* Wg = (const float4*)W;
  float4* Wp4 = (float4*)Wp;

  if constexpr (BF16IN) {
    const u16* xg = (const u16*)xin + rowBase * IC1;
    #pragma unroll
    for (int i = tid; i < RB * (IC1 / 8); i += 256) {
      int r = i / (IC1 / 8), c = i % (IC1 / 8);
      uint4 v = make_uint4(0u, 0u, 0u, 0u);
      if (rowBase + r < N) v = ((const uint4*)(xg + (long long)r * IC1))[c];
      float* dst = &xs[r][c * 8];
      dst[0] = bflo(v.x); dst[1] = bfhi(v.x);
      dst[2] = bflo(v.y); dst[3] = bfhi(v.y);
      dst[4] = bflo(v.z); dst[5] = bfhi(v.z);
      dst[6] = bflo(v.w); dst[7] = bfhi(v.w);
    }
  } else {
    const float4* xg = (const float4*)((const float*)xin + rowBase * IC1);
    #pragma unroll
    for (int i = tid; i < RB * (IC1 / 4); i += 256) {
      int r = i / (IC1 / 4), c = i % (IC1 / 4);
      float4 v = make_float4(0.f, 0.f, 0.f, 0.f);
      if (rowBase + r < N) v = xg[(long long)r * (IC1 / 4) + c];
      *(float4*)&xs[r][c * 4] = v;
    }
  }
  #pragma unroll
  for (int i = tid; i < KP * COLV; i += 256) Wp4[i] = Wg[i];
  __syncthreads();

  float4 acc[RPT];
  #pragma unroll
  for (int r = 0; r < RPT; ++r) acc[r] = make_float4(0.f, 0.f, 0.f, 0.f);
  const int row0 = tg * RPT;

  for (int p = 0;; ++p) {
    const int kbase = p * KP;
    #pragma unroll 4
    for (int k = 0; k < KP; k += 4) {
      float4 xk[RPT];
      #pragma unroll
      for (int r = 0; r < RPT; ++r) xk[r] = *(const float4*)&xs[row0 + r][kbase + k];
      #pragma unroll
      for (int kk = 0; kk < 4; ++kk) {
        float4 w = Wp4[(k + kk) * COLV + tx];
        #pragma unroll
        for (int r = 0; r < RPT; ++r) {
          float xv = (kk == 0) ? xk[r].x : (kk == 1) ? xk[r].y : (kk == 2) ? xk[r].z : xk[r].w;
          acc[r].x += xv * w.x; acc[r].y += xv * w.y;
          acc[r].z += xv * w.z; acc[r].w += xv * w.w;
        }
      }
    }
    if (p == NP - 1) break;
    __syncthreads();
    #pragma unroll
    for (int i = tid; i < KP * COLV; i += 256) Wp4[i] = Wg[(p + 1) * KP * COLV + i];
    __syncthreads();
  }

  #pragma unroll
  for (int r = 0; r < RPT; ++r) {
    long long row = rowBase + row0 + r;
    if (row < N)
      ((uint2*)((u16*)t + row * OC))[tx] =
          make_uint2(pack2bf(acc[r].x, acc[r].y), pack2bf(acc[r].z, acc[r].w));
  }
}

// out[v] = sum_{e: dst=v} t[src_e]*w_e + t[v]*dinv[v]^2 + bias (optional relu)
// One wave per node; G=CH/8 lanes per row (16B bf16x8 per lane), EPI=64/G
// edges gathered per iteration. w = dinv[s]*dinv[v] from L2-hot dinv table.
template<int CH>
__global__ __launch_bounds__(256) void k_agg(const u16* __restrict__ t,
                                             u16* __restrict__ out,
                                             const float* __restrict__ dinv,
                                             const int* __restrict__ rowst,
                                             const u32* __restrict__ csr,
                                             const float* __restrict__ bias,
                                             int N, int relu) {
  constexpr int G   = CH / 8;   // lanes per edge row (16 or 8)
  constexpr int EPI = 64 / G;   // edges per iteration (4 or 8)
  long long wid = ((long long)blockIdx.x * blockDim.x + threadIdx.x) >> 6;
  int lane = threadIdx.x & 63;
  if (wid >= N) return;
  int v = (int)wid;
  int sub = lane / G;           // edge slot
  int cl  = lane % G;           // 16B chunk within row
  float dv = dinv[v];
  float selfw = (sub == 0) ? dv * dv : 0.f;
  float acc[8];
  {
    uint4 u = ((const uint4*)(t + (long long)v * CH))[cl];
    acc[0] = bflo(u.x) * selfw; acc[1] = bfhi(u.x) * selfw;
    acc[2] = bflo(u.y) * selfw; acc[3] = bfhi(u.y) * selfw;
    acc[4] = bflo(u.z) * selfw; acc[5] = bfhi(u.z) * selfw;
    acc[6] = bflo(u.w) * selfw; acc[7] = bfhi(u.w) * selfw;
  }
  int st = rowst[v];
  int cnt = rowst[v + 1] - st;
  for (int base = 0; base < cnt; base += 64) {
    int m = min(64, cnt - base);
    int s = 0; float w = 0.f;
    if (lane < m) { s = (int)csr[st + base + lane]; w = dinv[s] * dv; }
    int iters = (m + EPI - 1) / EPI;
    #pragma unroll 2
    for (int j = 0; j < iters; ++j) {
      int src  = __shfl(s, j * EPI + sub);   // padded lanes give s=0,w=0
      float ww = __shfl(w, j * EPI + sub);
      uint4 u = ((const uint4*)(t + (long long)src * CH))[cl];
      acc[0] += bflo(u.x) * ww; acc[1] += bfhi(u.x) * ww;
      acc[2] += bflo(u.y) * ww; acc[3] += bfhi(u.y) * ww;
      acc[4] += bflo(u.z) * ww; acc[5] += bfhi(u.z) * ww;
      acc[6] += bflo(u.w) * ww; acc[7] += bfhi(u.w) * ww;
    }
  }
  #pragma unroll
  for (int off = G; off < 64; off <<= 1) {
    #pragma unroll
    for (int i = 0; i < 8; ++i) acc[i] += __shfl_xor(acc[i], off);
  }
  if (sub == 0) {
    float4 b0 = ((const float4*)bias)[cl * 2];
    float4 b1 = ((const float4*)bias)[cl * 2 + 1];
    float o[8] = {acc[0] + b0.x, acc[1] + b0.y, acc[2] + b0.z, acc[3] + b0.w,
                  acc[4] + b1.x, acc[5] + b1.y, acc[6] + b1.z, acc[7] + b1.w};
    if (relu) {
      #pragma unroll
      for (int i = 0; i < 8; ++i) o[i] = fmaxf(o[i], 0.f);
    }
    uint4 w4;
    w4.x = pack2bf(o[0], o[1]); w4.y = pack2bf(o[2], o[3]);
    w4.z = pack2bf(o[4], o[5]); w4.w = pack2bf(o[6], o[7]);
    ((uint4*)(out + (long long)v * CH))[cl] = w4;
  }
}

// pred[e] = dot(z[src_e], z[dst_e]) over 64 bf16 ch. 8 lanes/edge, 16B/lane.
__global__ __launch_bounds__(256) void k_decode(const u16* __restrict__ z,
                                                const void* pei, const void* nei,
                                                float* __restrict__ out,
                                                long long E, const int* flagbuf) {
  int f = flagbuf[0];
  long long g = ((long long)blockIdx.x * blockDim.x + threadIdx.x) >> 3;
  int wi = threadIdx.x & 7;
  if (g >= 2 * E) return;
  const void* ei = (g < E) ? pei : nei;
  long long e = (g < E) ? g : g - E;
  int s = getIdx(ei, e, f);
  int d = getIdx(ei, E + e, f);
  uint4 a = ((const uint4*)(z + (long long)s * OC2))[wi];
  uint4 b = ((const uint4*)(z + (long long)d * OC2))[wi];
  float p = bflo(a.x) * bflo(b.x) + bfhi(a.x) * bfhi(b.x)
          + bflo(a.y) * bflo(b.y) + bfhi(a.y) * bfhi(b.y)
          + bflo(a.z) * bflo(b.z) + bfhi(a.z) * bfhi(b.z)
          + bflo(a.w) * bflo(b.w) + bfhi(a.w) * bfhi(b.w);
  p += __shfl_xor(p, 4);
  p += __shfl_xor(p, 2);
  p += __shfl_xor(p, 1);
  if (wi == 0) out[g] = p;   // [0,E): pos, [E,2E): neg
}

extern "C" void kernel_launch(void* const* d_in, const int* in_sizes, int n_in,
                              void* d_out, int out_size, void* d_ws, size_t ws_size,
                              hipStream_t stream) {
  const float* x  = (const float*)d_in[0];
  const void*  pei = d_in[1];
  const void*  nei = d_in[2];
  const float* W1 = (const float*)d_in[3];
  const float* b1 = (const float*)d_in[4];
  const float* W2 = (const float*)d_in[5];
  const float* b2 = (const float*)d_in[6];
  float* out = (float*)d_out;

  const int       N  = in_sizes[0] / IC1;    // 100000
  const long long E  = in_sizes[1] / 2;      // 1600000
  const int       NB = (N + BNODES - 1) >> BSH;

  // ---- workspace carve (256B-aligned) ----
  char* p = (char*)d_ws;
  auto carve = [&](size_t bytes) { char* r = p; p += ((bytes + 255) & ~(size_t)255); return r; };
  int*   flagbuf = (int*)  carve(8);
  int*   deg     = (int*)  carve((size_t)N * 4);
  float* dinv    = (float*)carve((size_t)N * 4);
  int*   rowst   = (int*)  carve((size_t)(N + 1) * 4);
  int*   bcnt    = (int*)  carve((size_t)NB * 4);
  int*   boff    = (int*)  carve((size_t)(NB + 1) * 4);
  int*   gcur    = (int*)  carve((size_t)NB * 4);
  u32*   binned  = (u32*)  carve((size_t)E * 4);
  u32*   csr     = (u32*)  carve((size_t)E * 4);
  u16*   bufA    = (u16*)  carve((size_t)N * IC1 * 2);  // t1 / t2 (bf16)
  u16*   bufB    = (u16*)  carve((size_t)N * IC1 * 2);  // h1 / z  (bf16)

  const int B = 256;

  // ---- graph structure (shared by both convs) ----
  k_detect<<<1, B, 0, stream>>>(pei, E, N, flagbuf);
  k_init<<<dim3((N + B - 1) / B), B, 0, stream>>>(deg, bcnt, N, NB);
  k_hist<<<dim3((unsigned)((E + CHH - 1) / CHH)), B, 0, stream>>>(pei, E, flagbuf,
                                                                  deg, bcnt, NB);
  k_scan<<<1, B, 0, stream>>>(bcnt, boff, gcur, rowst, NB, N);
  k_bin<<<dim3((unsigned)((E + CHB - 1) / CHB)), B, 0, stream>>>(pei, E, flagbuf,
                                                                 gcur, binned, NB);
  k_fill2<<<dim3(NB), B, 0, stream>>>(binned, boff, deg, dinv, rowst, csr, N);

  // ---- conv1: t1 = x@W1 -> aggregate -> +b1, relu -> h1 ----
  k_gemm<OC1, false><<<dim3((N + 31) / 32), B, 0, stream>>>(x, W1, bufA, N);
  k_agg<OC1><<<dim3((N + 3) / 4), B, 0, stream>>>(bufA, bufB, dinv, rowst,
                                                  csr, b1, N, 1);

  // ---- conv2: t2 = h1@W2 -> aggregate -> +b2 -> z ----
  k_gemm<OC2, true><<<dim3((N + 63) / 64), B, 0, stream>>>(bufB, W2, bufA, N);
  k_agg<OC2><<<dim3((N + 3) / 4), B, 0, stream>>>(bufA, bufB, dinv, rowst,
                                                  csr, b2, N, 0);

  // ---- decode: pos & neg dot products ----
  long long groups = 2 * E;
  dim3 gD((unsigned)((groups * 8 + B - 1) / B));
  k_decode<<<gD, B, 0, stream>>>(bufB, pei, nei, out, E, flagbuf);
}

// Round 5
// 444.145 us; speedup vs baseline: 2.2860x; 1.2330x over previous
//
#include <hip/hip_runtime.h>

// LinkPredictionGNN: 2-layer GCN encode + dot-product decode.
// R5: (a) CSR build without any random global atomics -- k_hist is a pure
// LDS bucket histogram; deg/dinv/rowst derived per-bucket inside k_fill2
// from the binned window (sequential reads, coalesced writes). (b) GEMMs
// rewritten on mfma_f32_16x16x32_bf16 (W pre-transposed to K-contiguous
// bf16 by k_prepw; x tile + Wt staged in LDS, rows padded to 136 bf16 so
// fragment reads are only free 2-way bank conflicts). Gather kernels (agg,
// decode) unchanged -- they sit at the random-row-gather cache roofline.

#define IC1 128   // input channels (= hidden channels for conv2 input)
#define OC1 128   // conv1 output channels
#define OC2 64    // conv2 output channels

#define BSH    9            // bucket shift: 512 nodes per bucket
#define BNODES (1 << BSH)
#define NBMAX  512          // supports N <= 262144 (N = 100000 here)
#define CHB    8192         // edges per k_bin block
#define CHH    16384        // edges per k_hist block
// binned pack: src in bits [0,20), d_local in bits [20,29)  (requires N < 2^20)

typedef unsigned int u32;
typedef unsigned short u16;
typedef __attribute__((ext_vector_type(8))) short short8v;   // 8 bf16 = 4 VGPR
typedef __attribute__((ext_vector_type(4))) float f32x4;

// ---- bf16 helpers (RNE pack, bit-shift unpack) ----
__device__ __forceinline__ u16 f2bf(float f) {
  u32 u = __float_as_uint(f);
  u32 r = (u + 0x7fffu + ((u >> 16) & 1u)) >> 16;
  return (u16)r;
}
__device__ __forceinline__ u32 pack2bf(float lo, float hi) {
  return (u32)f2bf(lo) | ((u32)f2bf(hi) << 16);
}
__device__ __forceinline__ float bflo(u32 w) { return __uint_as_float(w << 16); }
__device__ __forceinline__ float bfhi(u32 w) { return __uint_as_float(w & 0xffff0000u); }

// Edge-index element: int64 per reference, int32 possible per harness doc.
__device__ __forceinline__ int getIdx(const void* p, long long i, int is64) {
  return is64 ? (int)((const long long*)p)[i] : ((const int*)p)[i];
}

// dtype flag + zero bcnt (NB <= NBMAX).
__global__ void k_detect(const void* pei, long long E, int n_nodes, int* flagbuf,
                         int* bcnt, int NB) {
  __shared__ int bad;
  if (threadIdx.x == 0) bad = 0;
  __syncthreads();
  long long cnt = E < 4096 ? E : 4096;
  const unsigned long long* p64 = (const unsigned long long*)pei;
  for (long long i = threadIdx.x; i < cnt; i += blockDim.x)
    if (p64[i] >= (unsigned long long)n_nodes) bad = 1;   // benign race
  for (int i = threadIdx.x; i < NB; i += blockDim.x) bcnt[i] = 0;
  __syncthreads();
  if (threadIdx.x == 0) flagbuf[0] = bad ? 0 : 1;
}

// Pure per-bucket edge histogram (LDS atomics only; no global deg atomics).
__global__ __launch_bounds__(256) void k_hist(const void* pei, long long E,
                                              const int* flagbuf, int* bcnt, int NB) {
  __shared__ int h[NBMAX];
  int f = flagbuf[0];
  for (int i = threadIdx.x; i < NB; i += 256) h[i] = 0;
  __syncthreads();
  long long e0 = (long long)blockIdx.x * CHH;
  long long e1 = min(E, e0 + CHH);
  for (long long e = e0 + threadIdx.x; e < e1; e += 256)
    atomicAdd(&h[getIdx(pei, E + e, f) >> BSH], 1);
  __syncthreads();
  for (int i = threadIdx.x; i < NB; i += 256)
    if (h[i]) atomicAdd(&bcnt[i], h[i]);
}

// Single-block exclusive scan of bucket counts -> boff / gcur; rowst[N]=E.
__global__ __launch_bounds__(256) void k_scan(const int* bcnt, int* boff,
                                              int* gcur, int* rowst, int NB, int N) {
  __shared__ int sa[256];
  __shared__ int carryS;
  if (threadIdx.x == 0) carryS = 0;
  __syncthreads();
  for (int base = 0; base < NB; base += 256) {
    int i = base + threadIdx.x;
    int v = (i < NB) ? bcnt[i] : 0;
    sa[threadIdx.x] = v;
    __syncthreads();
    for (int off = 1; off < 256; off <<= 1) {
      int t = (threadIdx.x >= off) ? sa[threadIdx.x - off] : 0;
      __syncthreads();
      sa[threadIdx.x] += t;
      __syncthreads();
    }
    int exc = sa[threadIdx.x] - v + carryS;
    if (i < NB) { boff[i] = exc; gcur[i] = exc; }
    __syncthreads();
    if (threadIdx.x == 255) carryS += sa[255];
    __syncthreads();
  }
  if (threadIdx.x == 0) { boff[NB] = carryS; rowst[N] = carryS; }
}

// LDS-staged partition: sort a CHB-edge chunk by bucket in LDS, flush each
// bucket's run contiguously to global binned[] (one cursor atomic per bucket).
__global__ __launch_bounds__(256) void k_bin(const void* pei, long long E,
                                             const int* flagbuf, int* gcur,
                                             u32* binned, int NB) {
  __shared__ u32 stage[CHB];
  __shared__ int h[NBMAX], lofs[NBMAX + 1], cur[NBMAX], gofs[NBMAX];
  __shared__ int sa[256];
  __shared__ int carryS;
  int f = flagbuf[0];
  int tid = threadIdx.x;
  for (int i = tid; i < NB; i += 256) h[i] = 0;
  if (tid == 0) carryS = 0;
  __syncthreads();
  long long e0 = (long long)blockIdx.x * CHB;
  long long e1 = min(E, e0 + CHB);
  int cc = (int)(e1 - e0);
  for (long long e = e0 + tid; e < e1; e += 256)
    atomicAdd(&h[getIdx(pei, E + e, f) >> BSH], 1);
  __syncthreads();
  // exclusive scan h -> lofs
  for (int base = 0; base < NB; base += 256) {
    int i = base + tid;
    int v = (i < NB) ? h[i] : 0;
    sa[tid] = v;
    __syncthreads();
    for (int off = 1; off < 256; off <<= 1) {
      int t = (tid >= off) ? sa[tid - off] : 0;
      __syncthreads();
      sa[tid] += t;
      __syncthreads();
    }
    int exc = sa[tid] - v + carryS;
    if (i < NB) { lofs[i] = exc; cur[i] = exc; }
    __syncthreads();
    if (tid == 255) carryS += sa[255];
    __syncthreads();
  }
  if (tid == 0) lofs[NB] = cc;
  __syncthreads();
  // scatter chunk into LDS staging, bucket-grouped
  for (long long e = e0 + tid; e < e1; e += 256) {
    int s = getIdx(pei, e, f);
    int d = getIdx(pei, E + e, f);
    int b = d >> BSH;
    int p = atomicAdd(&cur[b], 1);
    stage[p] = (u32)s | ((u32)(d & (BNODES - 1)) << 20);
  }
  __syncthreads();
  // claim global space per bucket
  for (int b = tid; b < NB; b += 256) {
    int cnt = cur[b] - lofs[b];
    gofs[b] = cnt ? (atomicAdd(&gcur[b], cnt) - lofs[b]) : 0;
  }
  __syncthreads();
  // flush: consecutive LDS slots -> consecutive global slots within each run
  for (int i = tid; i < cc; i += 256) {
    int lo = 0, hi = NB;   // invariant: lofs[lo] <= i < lofs[hi]
    while (hi - lo > 1) {
      int mid = (lo + hi) >> 1;
      if (lofs[mid] <= i) lo = mid; else hi = mid;
    }
    binned[(long long)i + gofs[lo]] = stage[i];
  }
}

// One block per bucket. Pass 1: LDS histogram of local dst -> deg -> dinv +
// rowst (coalesced writes). Pass 2: scatter bucket edges into the bucket's
// contiguous csr window (single XCD -> full-line writes). No global atomics.
__global__ __launch_bounds__(256) void k_fill2(const u32* __restrict__ binned,
                                               const int* __restrict__ boff,
                                               float* __restrict__ dinv,
                                               int* __restrict__ rowst,
                                               u32* __restrict__ csr, int N) {
  __shared__ int cnt[BNODES], sa[BNODES], sb[BNODES], cursor[BNODES];
  int b = blockIdx.x;
  int v0 = b << BSH;
  int nv = min(BNODES, N - v0);
  int tid = threadIdx.x;
  for (int i = tid; i < BNODES; i += 256) cnt[i] = 0;
  __syncthreads();
  int base = boff[b];
  int j1 = boff[b + 1];
  for (int j = base + tid; j < j1; j += 256)
    atomicAdd(&cnt[binned[j] >> 20], 1);
  __syncthreads();
  for (int i = tid; i < BNODES; i += 256) sa[i] = cnt[i];
  __syncthreads();
  int* A = sa; int* B = sb;
  #pragma unroll 1
  for (int off = 1; off < BNODES; off <<= 1) {   // inclusive Hillis-Steele
    for (int i = tid; i < BNODES; i += 256)
      B[i] = A[i] + ((i >= off) ? A[i - off] : 0);
    __syncthreads();
    int* t = A; A = B; B = t;
  }
  for (int i = tid; i < nv; i += 256) {
    int c = cnt[i];
    int exc = A[i] - c;
    rowst[v0 + i] = base + exc;
    cursor[i] = exc;
    dinv[v0 + i] = rsqrtf((float)(c + 1));   // + self-loop
  }
  __syncthreads();
  for (int j = base + tid; j < j1; j += 256) {
    u32 u = binned[j];
    int p = atomicAdd(&cursor[u >> 20], 1);
    csr[base + p] = u & 0xFFFFFu;
  }
}

// Pre-transpose W -> bf16 Wt[c][k] (K contiguous per output column).
__global__ void k_prepw(const float* __restrict__ W, u16* __restrict__ Wt,
                        int OC) {
  int i = blockIdx.x * blockDim.x + threadIdx.x;     // i = k*OC + c
  if (i >= 128 * OC) return;
  int k = i / OC, c = i % OC;
  Wt[c * 128 + k] = f2bf(W[i]);
}

// t = x @ W via mfma_f32_16x16x32_bf16. 4 waves/block, wave = 16 rows,
// CT = OC/16 col-tiles, K = 128 in 4 fragments. LDS rows padded to 136 bf16
// (272 B) so A/B fragment reads are free 2-way bank conflicts only.
// Layouts (m89/m91-verified): A row=lane&15, k=(lane>>4)*8+j (contiguous);
// B col=lane&15 from K-contiguous Wt; C/D col=lane&15, row=(lane>>4)*4+reg.
template<int OC, bool BF16IN>
__global__ __launch_bounds__(256) void k_gemm_mfma(const void* __restrict__ xin,
                                                   const u16* __restrict__ Wt,
                                                   u16* __restrict__ t, int N) {
  constexpr int CT = OC / 16;       // col tiles (8 or 4)
  constexpr int LW = 136;           // padded LDS row (bf16)
  __shared__ u16 xs[64][LW];        // 64 rows x 128 bf16 (+pad)
  __shared__ u16 ws[OC][LW];        // Wt staged
  const int tid = threadIdx.x;
  const int lane = tid & 63, wv = tid >> 6;
  const long long rowBase = (long long)blockIdx.x * 64;

  // stage x tile (64 rows x 128 ch -> bf16)
  if constexpr (BF16IN) {
    const u16* xg = (const u16*)xin;
    #pragma unroll
    for (int i = tid; i < 64 * 16; i += 256) {     // 16B chunks
      int r = i >> 4, c = i & 15;
      uint4 v = make_uint4(0u, 0u, 0u, 0u);
      if (rowBase + r < N) v = ((const uint4*)(xg + (rowBase + r) * IC1))[c];
      *(uint4*)&xs[r][c * 8] = v;
    }
  } else {
    const float* xg = (const float*)xin;
    #pragma unroll
    for (int i = tid; i < 64 * 16; i += 256) {
      int r = i >> 4, c = i & 15;
      uint4 o = make_uint4(0u, 0u, 0u, 0u);
      if (rowBase + r < N) {
        const float4* src = (const float4*)(xg + (rowBase + r) * IC1 + c * 8);
        float4 a = src[0], bq = src[1];
        o.x = pack2bf(a.x, a.y);  o.y = pack2bf(a.z, a.w);
        o.z = pack2bf(bq.x, bq.y); o.w = pack2bf(bq.z, bq.w);
      }
      *(uint4*)&xs[r][c * 8] = o;
    }
  }
  // stage Wt (OC rows x 128 bf16)
  #pragma unroll
  for (int i = tid; i < OC * 16; i += 256) {
    int r = i >> 4, c = i & 15;
    *(uint4*)&ws[r][c * 8] = ((const uint4*)(Wt + r * 128))[c];
  }
  __syncthreads();

  const int frow = lane & 15, fk = (lane >> 4) * 8;
  short8v a[4];
  #pragma unroll
  for (int kq = 0; kq < 4; ++kq)
    a[kq] = *(const short8v*)&xs[wv * 16 + frow][kq * 32 + fk];

  f32x4 acc[CT];
  #pragma unroll
  for (int ct = 0; ct < CT; ++ct) {
    acc[ct] = (f32x4){0.f, 0.f, 0.f, 0.f};
    #pragma unroll
    for (int kq = 0; kq < 4; ++kq) {
      short8v bfrag = *(const short8v*)&ws[ct * 16 + frow][kq * 32 + fk];
      acc[ct] = __builtin_amdgcn_mfma_f32_16x16x32_bf16(a[kq], bfrag, acc[ct], 0, 0, 0);
    }
  }

  const int crow0 = (lane >> 4) * 4, ccol = lane & 15;
  #pragma unroll
  for (int ct = 0; ct < CT; ++ct) {
    #pragma unroll
    for (int r = 0; r < 4; ++r) {
      long long row = rowBase + wv * 16 + crow0 + r;
      if (row < N) t[row * OC + ct * 16 + ccol] = f2bf(acc[ct][r]);
    }
  }
}

// out[v] = sum_{e: dst=v} t[src_e]*w_e + t[v]*dinv[v]^2 + bias (optional relu)
// One wave per node; G=CH/8 lanes per row (16B bf16x8 per lane), EPI=64/G
// edges gathered per iteration. w = dinv[s]*dinv[v] from L2-hot dinv table.
template<int CH>
__global__ __launch_bounds__(256) void k_agg(const u16* __restrict__ t,
                                             u16* __restrict__ out,
                                             const float* __restrict__ dinv,
                                             const int* __restrict__ rowst,
                                             const u32* __restrict__ csr,
                                             const float* __restrict__ bias,
                                             int N, int relu) {
  constexpr int G   = CH / 8;   // lanes per edge row (16 or 8)
  constexpr int EPI = 64 / G;   // edges per iteration (4 or 8)
  long long wid = ((long long)blockIdx.x * blockDim.x + threadIdx.x) >> 6;
  int lane = threadIdx.x & 63;
  if (wid >= N) return;
  int v = (int)wid;
  int sub = lane / G;           // edge slot
  int cl  = lane % G;           // 16B chunk within row
  float dv = dinv[v];
  float selfw = (sub == 0) ? dv * dv : 0.f;
  float acc[8];
  {
    uint4 u = ((const uint4*)(t + (long long)v * CH))[cl];
    acc[0] = bflo(u.x) * selfw; acc[1] = bfhi(u.x) * selfw;
    acc[2] = bflo(u.y) * selfw; acc[3] = bfhi(u.y) * selfw;
    acc[4] = bflo(u.z) * selfw; acc[5] = bfhi(u.z) * selfw;
    acc[6] = bflo(u.w) * selfw; acc[7] = bfhi(u.w) * selfw;
  }
  int st = rowst[v];
  int cnt = rowst[v + 1] - st;
  for (int base = 0; base < cnt; base += 64) {
    int m = min(64, cnt - base);
    int s = 0; float w = 0.f;
    if (lane < m) { s = (int)csr[st + base + lane]; w = dinv[s] * dv; }
    int iters = (m + EPI - 1) / EPI;
    #pragma unroll 2
    for (int j = 0; j < iters; ++j) {
      int src  = __shfl(s, j * EPI + sub);   // padded lanes give s=0,w=0
      float ww = __shfl(w, j * EPI + sub);
      uint4 u = ((const uint4*)(t + (long long)src * CH))[cl];
      acc[0] += bflo(u.x) * ww; acc[1] += bfhi(u.x) * ww;
      acc[2] += bflo(u.y) * ww; acc[3] += bfhi(u.y) * ww;
      acc[4] += bflo(u.z) * ww; acc[5] += bfhi(u.z) * ww;
      acc[6] += bflo(u.w) * ww; acc[7] += bfhi(u.w) * ww;
    }
  }
  #pragma unroll
  for (int off = G; off < 64; off <<= 1) {
    #pragma unroll
    for (int i = 0; i < 8; ++i) acc[i] += __shfl_xor(acc[i], off);
  }
  if (sub == 0) {
    float4 b0 = ((const float4*)bias)[cl * 2];
    float4 b1 = ((const float4*)bias)[cl * 2 + 1];
    float o[8] = {acc[0] + b0.x, acc[1] + b0.y, acc[2] + b0.z, acc[3] + b0.w,
                  acc[4] + b1.x, acc[5] + b1.y, acc[6] + b1.z, acc[7] + b1.w};
    if (relu) {
      #pragma unroll
      for (int i = 0; i < 8; ++i) o[i] = fmaxf(o[i], 0.f);
    }
    uint4 w4;
    w4.x = pack2bf(o[0], o[1]); w4.y = pack2bf(o[2], o[3]);
    w4.z = pack2bf(o[4], o[5]); w4.w = pack2bf(o[6], o[7]);
    ((uint4*)(out + (long long)v * CH))[cl] = w4;
  }
}

// pred[e] = dot(z[src_e], z[dst_e]) over 64 bf16 ch. 8 lanes/edge, 16B/lane.
__global__ __launch_bounds__(256) void k_decode(const u16* __restrict__ z,
                                                const void* pei, const void* nei,
                                                float* __restrict__ out,
                                                long long E, const int* flagbuf) {
  int f = flagbuf[0];
  long long g = ((long long)blockIdx.x * blockDim.x + threadIdx.x) >> 3;
  int wi = threadIdx.x & 7;
  if (g >= 2 * E) return;
  const void* ei = (g < E) ? pei : nei;
  long long e = (g < E) ? g : g - E;
  int s = getIdx(ei, e, f);
  int d = getIdx(ei, E + e, f);
  uint4 a = ((const uint4*)(z + (long long)s * OC2))[wi];
  uint4 b = ((const uint4*)(z + (long long)d * OC2))[wi];
  float p = bflo(a.x) * bflo(b.x) + bfhi(a.x) * bfhi(b.x)
          + bflo(a.y) * bflo(b.y) + bfhi(a.y) * bfhi(b.y)
          + bflo(a.z) * bflo(b.z) + bfhi(a.z) * bfhi(b.z)
          + bflo(a.w) * bflo(b.w) + bfhi(a.w) * bfhi(b.w);
  p += __shfl_xor(p, 4);
  p += __shfl_xor(p, 2);
  p += __shfl_xor(p, 1);
  if (wi == 0) out[g] = p;   // [0,E): pos, [E,2E): neg
}

extern "C" void kernel_launch(void* const* d_in, const int* in_sizes, int n_in,
                              void* d_out, int out_size, void* d_ws, size_t ws_size,
                              hipStream_t stream) {
  const float* x  = (const float*)d_in[0];
  const void*  pei = d_in[1];
  const void*  nei = d_in[2];
  const float* W1 = (const float*)d_in[3];
  const float* b1 = (const float*)d_in[4];
  const float* W2 = (const float*)d_in[5];
  const float* b2 = (const float*)d_in[6];
  float* out = (float*)d_out;

  const int       N  = in_sizes[0] / IC1;    // 100000
  const long long E  = in_sizes[1] / 2;      // 1600000
  const int       NB = (N + BNODES - 1) >> BSH;

  // ---- workspace carve (256B-aligned) ----
  char* p = (char*)d_ws;
  auto carve = [&](size_t bytes) { char* r = p; p += ((bytes + 255) & ~(size_t)255); return r; };
  int*   flagbuf = (int*)  carve(8);
  float* dinv    = (float*)carve((size_t)N * 4);
  int*   rowst   = (int*)  carve((size_t)(N + 1) * 4);
  int*   bcnt    = (int*)  carve((size_t)NB * 4);
  int*   boff    = (int*)  carve((size_t)(NB + 1) * 4);
  int*   gcur    = (int*)  carve((size_t)NB * 4);
  u32*   binned  = (u32*)  carve((size_t)E * 4);
  u32*   csr     = (u32*)  carve((size_t)E * 4);
  u16*   Wt      = (u16*)  carve((size_t)128 * 128 * 2);  // reused W1 then W2
  u16*   bufA    = (u16*)  carve((size_t)N * IC1 * 2);    // t1 / t2 (bf16)
  u16*   bufB    = (u16*)  carve((size_t)N * IC1 * 2);    // h1 / z  (bf16)

  const int B = 256;

  // ---- graph structure (shared by both convs) ----
  k_detect<<<1, B, 0, stream>>>(pei, E, N, flagbuf, bcnt, NB);
  k_hist<<<dim3((unsigned)((E + CHH - 1) / CHH)), B, 0, stream>>>(pei, E, flagbuf,
                                                                  bcnt, NB);
  k_scan<<<1, B, 0, stream>>>(bcnt, boff, gcur, rowst, NB, N);
  k_bin<<<dim3((unsigned)((E + CHB - 1) / CHB)), B, 0, stream>>>(pei, E, flagbuf,
                                                                 gcur, binned, NB);
  k_fill2<<<dim3(NB), B, 0, stream>>>(binned, boff, dinv, rowst, csr, N);

  // ---- conv1: t1 = x@W1 -> aggregate -> +b1, relu -> h1 ----
  k_prepw<<<dim3((128 * OC1 + B - 1) / B), B, 0, stream>>>(W1, Wt, OC1);
  k_gemm_mfma<OC1, false><<<dim3((N + 63) / 64), B, 0, stream>>>(x, Wt, bufA, N);
  k_agg<OC1><<<dim3((N + 3) / 4), B, 0, stream>>>(bufA, bufB, dinv, rowst,
                                                  csr, b1, N, 1);

  // ---- conv2: t2 = h1@W2 -> aggregate -> +b2 -> z ----
  k_prepw<<<dim3((128 * OC2 + B - 1) / B), B, 0, stream>>>(W2, Wt, OC2);
  k_gemm_mfma<OC2, true><<<dim3((N + 63) / 64), B, 0, stream>>>(bufB, Wt, bufA, N);
  k_agg<OC2><<<dim3((N + 3) / 4), B, 0, stream>>>(bufA, bufB, dinv, rowst,
                                                  csr, b2, N, 0);

  // ---- decode: pos & neg dot products ----
  long long groups = 2 * E;
  dim3 gD((unsigned)((groups * 8 + B - 1) / B));
  k_decode<<<gD, B, 0, stream>>>(bufB, pei, nei, out, E, flagbuf);
}

// Round 8
// 412.688 us; speedup vs baseline: 2.4602x; 1.0762x over previous
//
#include <hip/hip_runtime.h>

// LinkPredictionGNN: 2-layer GCN encode + dot-product decode.
// R6 (2nd resubmit; two consecutive GPU-acquisition timeouts, kernel still
// unmeasured): (a) k_scan dispatch eliminated -- k_bin derives bucket offsets
// from an in-LDS scan of the (L2-hot, 784B) bcnt array + zero-based gcur0
// claims; k_fill2 block-reduces its own window base. (b) hist/bin chunks 4096
// (391 blocks, better CU saturation); fill2 at 512 threads. (c) GEMM reads
// B-frags directly from L1/L2-resident Wt (no W LDS panel), 128-row x-tile,
// 2 MFMAs per B-frag load. (d) agg inner loop unroll 4. Decode untouched: it
// is L2-fill-bound at ~3 TB/s (291 MB fill / 96 us, stable across rounds).

#define IC1 128   // input channels (= hidden channels for conv2 input)
#define OC1 128   // conv1 output channels
#define OC2 64    // conv2 output channels

#define BSH    9            // bucket shift: 512 nodes per bucket
#define BNODES (1 << BSH)
#define NBMAX  512          // supports N <= 262144 (N = 100000 here)
#define CHB    4096         // edges per k_bin block
#define CHH    4096         // edges per k_hist block
// binned pack: src in bits [0,20), d_local in bits [20,29)  (requires N < 2^20)

typedef unsigned int u32;
typedef unsigned short u16;
typedef __attribute__((ext_vector_type(8))) short short8v;   // 8 bf16 = 4 VGPR
typedef __attribute__((ext_vector_type(4))) float f32x4;

// ---- bf16 helpers (RNE pack, bit-shift unpack) ----
__device__ __forceinline__ u16 f2bf(float f) {
  u32 u = __float_as_uint(f);
  u32 r = (u + 0x7fffu + ((u >> 16) & 1u)) >> 16;
  return (u16)r;
}
__device__ __forceinline__ u32 pack2bf(float lo, float hi) {
  return (u32)f2bf(lo) | ((u32)f2bf(hi) << 16);
}
__device__ __forceinline__ float bflo(u32 w) { return __uint_as_float(w << 16); }
__device__ __forceinline__ float bfhi(u32 w) { return __uint_as_float(w & 0xffff0000u); }

// Edge-index element: int64 per reference, int32 possible per harness doc.
__device__ __forceinline__ int getIdx(const void* p, long long i, int is64) {
  return is64 ? (int)((const long long*)p)[i] : ((const int*)p)[i];
}

// dtype flag + zero bcnt/gcur0.
__global__ void k_detect(const void* pei, long long E, int n_nodes, int* flagbuf,
                         int* bcnt, int* gcur0, int NB) {
  __shared__ int bad;
  if (threadIdx.x == 0) bad = 0;
  __syncthreads();
  long long cnt = E < 4096 ? E : 4096;
  const unsigned long long* p64 = (const unsigned long long*)pei;
  for (long long i = threadIdx.x; i < cnt; i += blockDim.x)
    if (p64[i] >= (unsigned long long)n_nodes) bad = 1;   // benign race
  for (int i = threadIdx.x; i < NB; i += blockDim.x) { bcnt[i] = 0; gcur0[i] = 0; }
  __syncthreads();
  if (threadIdx.x == 0) flagbuf[0] = bad ? 0 : 1;
}

// Pure per-bucket edge histogram (LDS atomics only).
__global__ __launch_bounds__(256) void k_hist(const void* pei, long long E,
                                              const int* flagbuf, int* bcnt, int NB) {
  __shared__ int h[NBMAX];
  int f = flagbuf[0];
  for (int i = threadIdx.x; i < NB; i += 256) h[i] = 0;
  __syncthreads();
  long long e0 = (long long)blockIdx.x * CHH;
  long long e1 = min(E, e0 + CHH);
  for (long long e = e0 + threadIdx.x; e < e1; e += 256)
    atomicAdd(&h[getIdx(pei, E + e, f) >> BSH], 1);
  __syncthreads();
  for (int i = threadIdx.x; i < NB; i += 256)
    if (h[i]) atomicAdd(&bcnt[i], h[i]);
}

// LDS-staged partition. Bucket base offsets (prefix of bcnt) computed in-LDS;
// per-chunk space claimed via zero-based gcur0 atomics.
__global__ __launch_bounds__(256) void k_bin(const void* pei, long long E,
                                             const int* flagbuf, const int* bcnt,
                                             int* gcur0, u32* binned, int NB) {
  __shared__ u32 stage[CHB];
  __shared__ int h[NBMAX], lofs[NBMAX + 1], cur[NBMAX], gofs[NBMAX], gboff[NBMAX];
  __shared__ int sa[256];
  __shared__ int carryS;
  int f = flagbuf[0];
  int tid = threadIdx.x;
  for (int i = tid; i < NB; i += 256) h[i] = 0;
  if (tid == 0) carryS = 0;
  __syncthreads();
  long long e0 = (long long)blockIdx.x * CHB;
  long long e1 = min(E, e0 + CHB);
  int cc = (int)(e1 - e0);
  for (long long e = e0 + tid; e < e1; e += 256)
    atomicAdd(&h[getIdx(pei, E + e, f) >> BSH], 1);
  __syncthreads();
  // exclusive scan h -> lofs
  for (int base = 0; base < NB; base += 256) {
    int i = base + tid;
    int v = (i < NB) ? h[i] : 0;
    sa[tid] = v;
    __syncthreads();
    for (int off = 1; off < 256; off <<= 1) {
      int t = (tid >= off) ? sa[tid - off] : 0;
      __syncthreads();
      sa[tid] += t;
      __syncthreads();
    }
    int exc = sa[tid] - v + carryS;
    if (i < NB) { lofs[i] = exc; cur[i] = exc; }
    __syncthreads();
    if (tid == 255) carryS += sa[255];
    __syncthreads();
  }
  if (tid == 0) { lofs[NB] = cc; carryS = 0; }
  __syncthreads();
  // exclusive scan bcnt -> gboff (global bucket offsets; bcnt is L2-hot)
  for (int base = 0; base < NB; base += 256) {
    int i = base + tid;
    int v = (i < NB) ? bcnt[i] : 0;
    sa[tid] = v;
    __syncthreads();
    for (int off = 1; off < 256; off <<= 1) {
      int t = (tid >= off) ? sa[tid - off] : 0;
      __syncthreads();
      sa[tid] += t;
      __syncthreads();
    }
    int exc = sa[tid] - v + carryS;
    if (i < NB) gboff[i] = exc;
    __syncthreads();
    if (tid == 255) carryS += sa[255];
    __syncthreads();
  }
  // scatter chunk into LDS staging, bucket-grouped
  for (long long e = e0 + tid; e < e1; e += 256) {
    int s = getIdx(pei, e, f);
    int d = getIdx(pei, E + e, f);
    int b = d >> BSH;
    int p = atomicAdd(&cur[b], 1);
    stage[p] = (u32)s | ((u32)(d & (BNODES - 1)) << 20);
  }
  __syncthreads();
  // claim global space per bucket
  for (int b = tid; b < NB; b += 256) {
    int cnt = cur[b] - lofs[b];
    gofs[b] = cnt ? (gboff[b] + atomicAdd(&gcur0[b], cnt) - lofs[b]) : 0;
  }
  __syncthreads();
  // flush: consecutive LDS slots -> consecutive global slots within each run
  for (int i = tid; i < cc; i += 256) {
    int lo = 0, hi = NB;   // invariant: lofs[lo] <= i < lofs[hi]
    while (hi - lo > 1) {
      int mid = (lo + hi) >> 1;
      if (lofs[mid] <= i) lo = mid; else hi = mid;
    }
    binned[(long long)i + gofs[lo]] = stage[i];
  }
}

// One block per bucket. Window base = block-reduce prefix of bcnt. Pass 1:
// LDS histogram of local dst -> deg -> dinv + rowst (coalesced). Pass 2:
// scatter bucket edges into the bucket's contiguous csr window.
__global__ __launch_bounds__(512) void k_fill2(const u32* __restrict__ binned,
                                               const int* __restrict__ bcnt,
                                               float* __restrict__ dinv,
                                               int* __restrict__ rowst,
                                               u32* __restrict__ csr, int N, int NB) {
  __shared__ int cnt[BNODES], sa[BNODES], sb[BNODES], cursor[BNODES];
  __shared__ int redu[8];
  __shared__ int baseS;
  int b = blockIdx.x;
  int v0 = b << BSH;
  int nv = min(BNODES, N - v0);
  int tid = threadIdx.x;
  // base = sum(bcnt[0..b))
  int part = 0;
  for (int i = tid; i < b; i += 512) part += bcnt[i];
  #pragma unroll
  for (int off = 32; off; off >>= 1) part += __shfl_down(part, off);
  if ((tid & 63) == 0) redu[tid >> 6] = part;
  for (int i = tid; i < BNODES; i += 512) cnt[i] = 0;
  __syncthreads();
  if (tid == 0) {
    int s = 0;
    #pragma unroll
    for (int w = 0; w < 8; ++w) s += redu[w];
    baseS = s;
  }
  __syncthreads();
  int base = baseS;
  int j1 = base + bcnt[b];
  for (int j = base + tid; j < j1; j += 512)
    atomicAdd(&cnt[binned[j] >> 20], 1);
  __syncthreads();
  sa[tid] = cnt[tid];
  __syncthreads();
  int* A = sa; int* B = sb;
  #pragma unroll 1
  for (int off = 1; off < BNODES; off <<= 1) {   // inclusive Hillis-Steele
    B[tid] = A[tid] + ((tid >= off) ? A[tid - off] : 0);
    __syncthreads();
    int* t = A; A = B; B = t;
  }
  if (tid < nv) {
    int c = cnt[tid];
    int exc = A[tid] - c;
    rowst[v0 + tid] = base + exc;
    cursor[tid] = exc;
    dinv[v0 + tid] = rsqrtf((float)(c + 1));   // + self-loop
  }
  if (b == NB - 1 && tid == 0) rowst[N] = j1;
  __syncthreads();
  for (int j = base + tid; j < j1; j += 512) {
    u32 u = binned[j];
    int p = atomicAdd(&cursor[u >> 20], 1);
    csr[base + p] = u & 0xFFFFFu;
  }
}

// Pre-transpose both weights -> bf16 Wt[c][k] (K contiguous per out column).
__global__ void k_prepw(const float* __restrict__ W1, const float* __restrict__ W2,
                        u16* __restrict__ Wt1, u16* __restrict__ Wt2) {
  int i = blockIdx.x * blockDim.x + threadIdx.x;
  if (i < 128 * OC1) {
    int k = i / OC1, c = i % OC1;
    Wt1[c * 128 + k] = f2bf(W1[i]);
  } else {
    int j = i - 128 * OC1;
    if (j < 128 * OC2) {
      int k = j / OC2, c = j % OC2;
      Wt2[c * 128 + k] = f2bf(W2[j]);
    }
  }
}

// t = x @ W via mfma_f32_16x16x32_bf16. 128-row x-tile in LDS (padded rows);
// B-fragments read directly from L1/L2-resident Wt (no LDS panel). 4 waves,
// wave = 32 rows (2 row-tiles), 2 MFMAs per B-frag load, 64 MFMA/wave.
// Layouts (R5-validated): A row=lane&15, k=(lane>>4)*8+j; B out-col=lane&15
// from K-contiguous Wt; C/D col=lane&15, row=(lane>>4)*4+reg.
template<int OC, bool BF16IN>
__global__ __launch_bounds__(256) void k_gemm_mfma(const void* __restrict__ xin,
                                                   const u16* __restrict__ Wt,
                                                   u16* __restrict__ t, int N) {
  constexpr int CT = OC / 16;       // col tiles (8 or 4)
  constexpr int LW = 136;           // padded LDS row (bf16): 272B stride
  __shared__ u16 xs[128][LW];
  const int tid = threadIdx.x;
  const int lane = tid & 63, wv = tid >> 6;
  const long long rowBase = (long long)blockIdx.x * 128;

  if constexpr (BF16IN) {
    const u16* xg = (const u16*)xin;
    #pragma unroll
    for (int i = tid; i < 128 * 16; i += 256) {    // 16B chunks
      int r = i >> 4, c = i & 15;
      uint4 v = make_uint4(0u, 0u, 0u, 0u);
      if (rowBase + r < N) v = ((const uint4*)(xg + (rowBase + r) * IC1))[c];
      *(uint4*)&xs[r][c * 8] = v;
    }
  } else {
    const float* xg = (const float*)xin;
    #pragma unroll
    for (int i = tid; i < 128 * 16; i += 256) {
      int r = i >> 4, c = i & 15;
      uint4 o = make_uint4(0u, 0u, 0u, 0u);
      if (rowBase + r < N) {
        const float4* src = (const float4*)(xg + (rowBase + r) * IC1 + c * 8);
        float4 a = src[0], bq = src[1];
        o.x = pack2bf(a.x, a.y);  o.y = pack2bf(a.z, a.w);
        o.z = pack2bf(bq.x, bq.y); o.w = pack2bf(bq.z, bq.w);
      }
      *(uint4*)&xs[r][c * 8] = o;
    }
  }
  __syncthreads();

  const int frow = lane & 15, fk = (lane >> 4) * 8;
  short8v a[2][4];
  #pragma unroll
  for (int rt = 0; rt < 2; ++rt)
    #pragma unroll
    for (int kq = 0; kq < 4; ++kq)
      a[rt][kq] = *(const short8v*)&xs[wv * 32 + rt * 16 + frow][kq * 32 + fk];

  f32x4 acc[2][CT];
  #pragma unroll
  for (int ct = 0; ct < CT; ++ct) {
    acc[0][ct] = (f32x4){0.f, 0.f, 0.f, 0.f};
    acc[1][ct] = (f32x4){0.f, 0.f, 0.f, 0.f};
    #pragma unroll
    for (int kq = 0; kq < 4; ++kq) {
      short8v bfrag = *(const short8v*)(Wt + (ct * 16 + frow) * 128 + kq * 32 + fk);
      acc[0][ct] = __builtin_amdgcn_mfma_f32_16x16x32_bf16(a[0][kq], bfrag, acc[0][ct], 0, 0, 0);
      acc[1][ct] = __builtin_amdgcn_mfma_f32_16x16x32_bf16(a[1][kq], bfrag, acc[1][ct], 0, 0, 0);
    }
  }

  const int crow0 = (lane >> 4) * 4, ccol = lane & 15;
  #pragma unroll
  for (int rt = 0; rt < 2; ++rt)
    #pragma unroll
    for (int ct = 0; ct < CT; ++ct)
      #pragma unroll
      for (int r = 0; r < 4; ++r) {
        long long row = rowBase + wv * 32 + rt * 16 + crow0 + r;
        if (row < N) t[row * OC + ct * 16 + ccol] = f2bf(acc[rt][ct][r]);
      }
}

// out[v] = sum_{e: dst=v} t[src_e]*w_e + t[v]*dinv[v]^2 + bias (optional relu)
// One wave per node; G=CH/8 lanes per row (16B bf16x8 per lane), EPI=64/G
// edges gathered per iteration. w = dinv[s]*dinv[v] from L2-hot dinv table.
template<int CH>
__global__ __launch_bounds__(256) void k_agg(const u16* __restrict__ t,
                                             u16* __restrict__ out,
                                             const float* __restrict__ dinv,
                                             const int* __restrict__ rowst,
                                             const u32* __restrict__ csr,
                                             const float* __restrict__ bias,
                                             int N, int relu) {
  constexpr int G   = CH / 8;   // lanes per edge row (16 or 8)
  constexpr int EPI = 64 / G;   // edges per iteration (4 or 8)
  long long wid = ((long long)blockIdx.x * blockDim.x + threadIdx.x) >> 6;
  int lane = threadIdx.x & 63;
  if (wid >= N) return;
  int v = (int)wid;
  int sub = lane / G;           // edge slot
  int cl  = lane % G;           // 16B chunk within row
  float dv = dinv[v];
  float selfw = (sub == 0) ? dv * dv : 0.f;
  float acc[8];
  {
    uint4 u = ((const uint4*)(t + (long long)v * CH))[cl];
    acc[0] = bflo(u.x) * selfw; acc[1] = bfhi(u.x) * selfw;
    acc[2] = bflo(u.y) * selfw; acc[3] = bfhi(u.y) * selfw;
    acc[4] = bflo(u.z) * selfw; acc[5] = bfhi(u.z) * selfw;
    acc[6] = bflo(u.w) * selfw; acc[7] = bfhi(u.w) * selfw;
  }
  int st = rowst[v];
  int cnt = rowst[v + 1] - st;
  for (int base = 0; base < cnt; base += 64) {
    int m = min(64, cnt - base);
    int s = 0; float w = 0.f;
    if (lane < m) { s = (int)csr[st + base + lane]; w = dinv[s] * dv; }
    int iters = (m + EPI - 1) / EPI;
    #pragma unroll 4
    for (int j = 0; j < iters; ++j) {
      int src  = __shfl(s, j * EPI + sub);   // padded lanes give s=0,w=0
      float ww = __shfl(w, j * EPI + sub);
      uint4 u = ((const uint4*)(t + (long long)src * CH))[cl];
      acc[0] += bflo(u.x) * ww; acc[1] += bfhi(u.x) * ww;
      acc[2] += bflo(u.y) * ww; acc[3] += bfhi(u.y) * ww;
      acc[4] += bflo(u.z) * ww; acc[5] += bfhi(u.z) * ww;
      acc[6] += bflo(u.w) * ww; acc[7] += bfhi(u.w) * ww;
    }
  }
  #pragma unroll
  for (int off = G; off < 64; off <<= 1) {
    #pragma unroll
    for (int i = 0; i < 8; ++i) acc[i] += __shfl_xor(acc[i], off);
  }
  if (sub == 0) {
    float4 b0 = ((const float4*)bias)[cl * 2];
    float4 b1 = ((const float4*)bias)[cl * 2 + 1];
    float o[8] = {acc[0] + b0.x, acc[1] + b0.y, acc[2] + b0.z, acc[3] + b0.w,
                  acc[4] + b1.x, acc[5] + b1.y, acc[6] + b1.z, acc[7] + b1.w};
    if (relu) {
      #pragma unroll
      for (int i = 0; i < 8; ++i) o[i] = fmaxf(o[i], 0.f);
    }
    uint4 w4;
    w4.x = pack2bf(o[0], o[1]); w4.y = pack2bf(o[2], o[3]);
    w4.z = pack2bf(o[4], o[5]); w4.w = pack2bf(o[6], o[7]);
    ((uint4*)(out + (long long)v * CH))[cl] = w4;
  }
}

// pred[e] = dot(z[src_e], z[dst_e]) over 64 bf16 ch. 8 lanes/edge, 16B/lane.
__global__ __launch_bounds__(256) void k_decode(const u16* __restrict__ z,
                                                const void* pei, const void* nei,
                                                float* __restrict__ out,
                                                long long E, const int* flagbuf) {
  int f = flagbuf[0];
  long long g = ((long long)blockIdx.x * blockDim.x + threadIdx.x) >> 3;
  int wi = threadIdx.x & 7;
  if (g >= 2 * E) return;
  const void* ei = (g < E) ? pei : nei;
  long long e = (g < E) ? g : g - E;
  int s = getIdx(ei, e, f);
  int d = getIdx(ei, E + e, f);
  uint4 a = ((const uint4*)(z + (long long)s * OC2))[wi];
  uint4 b = ((const uint4*)(z + (long long)d * OC2))[wi];
  float p = bflo(a.x) * bflo(b.x) + bfhi(a.x) * bfhi(b.x)
          + bflo(a.y) * bflo(b.y) + bfhi(a.y) * bfhi(b.y)
          + bflo(a.z) * bflo(b.z) + bfhi(a.z) * bfhi(b.z)
          + bflo(a.w) * bflo(b.w) + bfhi(a.w) * bfhi(b.w);
  p += __shfl_xor(p, 4);
  p += __shfl_xor(p, 2);
  p += __shfl_xor(p, 1);
  if (wi == 0) out[g] = p;   // [0,E): pos, [E,2E): neg
}

extern "C" void kernel_launch(void* const* d_in, const int* in_sizes, int n_in,
                              void* d_out, int out_size, void* d_ws, size_t ws_size,
                              hipStream_t stream) {
  const float* x  = (const float*)d_in[0];
  const void*  pei = d_in[1];
  const void*  nei = d_in[2];
  const float* W1 = (const float*)d_in[3];
  const float* b1 = (const float*)d_in[4];
  const float* W2 = (const float*)d_in[5];
  const float* b2 = (const float*)d_in[6];
  float* out = (float*)d_out;

  const int       N  = in_sizes[0] / IC1;    // 100000
  const long long E  = in_sizes[1] / 2;      // 1600000
  const int       NB = (N + BNODES - 1) >> BSH;

  // ---- workspace carve (256B-aligned) ----
  char* p = (char*)d_ws;
  auto carve = [&](size_t bytes) { char* r = p; p += ((bytes + 255) & ~(size_t)255); return r; };
  int*   flagbuf = (int*)  carve(8);
  float* dinv    = (float*)carve((size_t)N * 4);
  int*   rowst   = (int*)  carve((size_t)(N + 1) * 4);
  int*   bcnt    = (int*)  carve((size_t)NB * 4);
  int*   gcur0   = (int*)  carve((size_t)NB * 4);
  u32*   binned  = (u32*)  carve((size_t)E * 4);
  u32*   csr     = (u32*)  carve((size_t)E * 4);
  u16*   Wt1     = (u16*)  carve((size_t)128 * OC1 * 2);
  u16*   Wt2     = (u16*)  carve((size_t)128 * OC2 * 2);
  u16*   bufA    = (u16*)  carve((size_t)N * IC1 * 2);    // t1 / t2 (bf16)
  u16*   bufB    = (u16*)  carve((size_t)N * IC1 * 2);    // h1 / z  (bf16)

  const int B = 256;

  // ---- graph structure (shared by both convs) ----
  k_detect<<<1, B, 0, stream>>>(pei, E, N, flagbuf, bcnt, gcur0, NB);
  k_hist<<<dim3((unsigned)((E + CHH - 1) / CHH)), B, 0, stream>>>(pei, E, flagbuf,
                                                                  bcnt, NB);
  k_bin<<<dim3((unsigned)((E + CHB - 1) / CHB)), B, 0, stream>>>(pei, E, flagbuf,
                                                                 bcnt, gcur0,
                                                                 binned, NB);
  k_fill2<<<dim3(NB), 512, 0, stream>>>(binned, bcnt, dinv, rowst, csr, N, NB);

  // ---- weights ----
  k_prepw<<<dim3((128 * (OC1 + OC2) + B - 1) / B), B, 0, stream>>>(W1, W2, Wt1, Wt2);

  // ---- conv1: t1 = x@W1 -> aggregate -> +b1, relu -> h1 ----
  k_gemm_mfma<OC1, false><<<dim3((N + 127) / 128), B, 0, stream>>>(x, Wt1, bufA, N);
  k_agg<OC1><<<dim3((N + 3) / 4), B, 0, stream>>>(bufA, bufB, dinv, rowst,
                                                  csr, b1, N, 1);

  // ---- conv2: t2 = h1@W2 -> aggregate -> +b2 -> z ----
  k_gemm_mfma<OC2, true><<<dim3((N + 127) / 128), B, 0, stream>>>(bufB, Wt2, bufA, N);
  k_agg<OC2><<<dim3((N + 3) / 4), B, 0, stream>>>(bufA, bufB, dinv, rowst,
                                                  csr, b2, N, 0);

  // ---- decode: pos & neg dot products ----
  long long groups = 2 * E;
  dim3 gD((unsigned)((groups * 8 + B - 1) / B));
  k_decode<<<gD, B, 0, stream>>>(bufB, pei, nei, out, E, flagbuf);
}